// Round 2
// baseline (8536.581 us; speedup 1.0000x reference)
//
#include <hip/hip_runtime.h>
#include <hip/hip_bf16.h>
#include <math.h>

namespace {

constexpr int Bsz = 4;
constexpr int L   = 2048;
constexpr int D   = 1024;
constexpr int DI  = 2048;
constexpr int DSTATE = 16;
constexpr int DTR = 64;
constexpr int ML  = Bsz * L; // 8192 rows

// ---------------- activations ----------------
template<int ACT>
__device__ __forceinline__ float activate(float x) {
  if (ACT == 1) { return x / (1.f + expf(-x)); }                        // silu
  if (ACT == 2) { return 0.5f * x * (1.f + erff(x * 0.7071067811865475f)); } // exact gelu
  if (ACT == 3) { return (x > 20.f) ? x : log1pf(expf(x)); }            // softplus
  return x;
}

// ---------------- tiled f32 GEMM: C = act(A * W^T + bias) ----------------
// A: (M x K) row-major, row stride lda; W: (N x K) row-major stride K.
// BF16_OUT: C stored as bf16 (row stride ldc elems), else f32.
template<int ACT, bool HAS_BIAS, bool BF16_OUT>
__global__ __launch_bounds__(256) void gemm_bt(
    const float* __restrict__ A, long lda,
    const float* __restrict__ W,
    const float* __restrict__ bias,
    void* __restrict__ Cp, long ldc,
    int N, int K)
{
  constexpr int BM = 128, BN = 64, BK = 16;
  __shared__ float As[BK][BM + 4];
  __shared__ float Ws[BK][BN + 4];
  const int bm = blockIdx.y * BM;
  const int bn = blockIdx.x * BN;
  const int tid = threadIdx.x;
  const int ty = tid >> 4, tx = tid & 15;
  float acc[8][4] = {};
  for (int k0 = 0; k0 < K; k0 += BK) {
    #pragma unroll
    for (int l = 0; l < 2; ++l) {
      const int id = tid + l * 256;
      const int m  = id >> 2;
      const int kq = id & 3;
      const float4 v = *reinterpret_cast<const float4*>(A + (long)(bm + m) * lda + k0 + kq * 4);
      As[kq*4+0][m] = v.x; As[kq*4+1][m] = v.y; As[kq*4+2][m] = v.z; As[kq*4+3][m] = v.w;
    }
    {
      const int n  = tid >> 2;
      const int kq = tid & 3;
      float4 v = make_float4(0.f, 0.f, 0.f, 0.f);
      if (bn + n < N)
        v = *reinterpret_cast<const float4*>(W + (long)(bn + n) * K + k0 + kq * 4);
      Ws[kq*4+0][n] = v.x; Ws[kq*4+1][n] = v.y; Ws[kq*4+2][n] = v.z; Ws[kq*4+3][n] = v.w;
    }
    __syncthreads();
    #pragma unroll
    for (int kk = 0; kk < BK; ++kk) {
      float a[8], bb[4];
      #pragma unroll
      for (int i = 0; i < 8; ++i) a[i] = As[kk][ty*8 + i];
      #pragma unroll
      for (int j = 0; j < 4; ++j) bb[j] = Ws[kk][tx*4 + j];
      #pragma unroll
      for (int i = 0; i < 8; ++i)
        #pragma unroll
        for (int j = 0; j < 4; ++j)
          acc[i][j] = fmaf(a[i], bb[j], acc[i][j]);
    }
    __syncthreads();
  }
  const int n0 = bn + tx * 4;
  if (n0 < N) {
    #pragma unroll
    for (int i = 0; i < 8; ++i) {
      const int m = bm + ty * 8 + i;
      float vv[4];
      #pragma unroll
      for (int j = 0; j < 4; ++j) {
        float v = acc[i][j];
        if (HAS_BIAS) v += bias[n0 + j];
        vv[j] = activate<ACT>(v);
      }
      if (BF16_OUT) {
        __hip_bfloat16 h[4];
        #pragma unroll
        for (int j = 0; j < 4; ++j) h[j] = __float2bfloat16(vv[j]);
        *reinterpret_cast<ushort4*>((__hip_bfloat16*)Cp + (long)m * ldc + n0) =
            *reinterpret_cast<ushort4*>(h);
      } else {
        float4 o; o.x = vv[0]; o.y = vv[1]; o.z = vv[2]; o.w = vv[3];
        *reinterpret_cast<float4*>((float*)Cp + (long)m * ldc + n0) = o;
      }
    }
  }
}

// ---------------- depthwise causal conv (k=4) + silu ----------------
// reads x_in (ML x DI, f32), writes xc (ML x DI, f32)
__global__ __launch_bounds__(256) void conv_silu(
    const float* __restrict__ xin,
    const float* __restrict__ w,     // (DI, 4)
    const float* __restrict__ bias,  // (DI)
    float* __restrict__ xc)
{
  const int idx = blockIdx.x * 256 + threadIdx.x;   // over ML*DI/4
  const int D4 = DI / 4;
  const int d  = (idx % D4) * 4;
  const int bt = idx / D4;           // 0..ML-1
  const int t  = bt & (L - 1);
  const int b  = bt >> 11;
  const float4 w0 = *reinterpret_cast<const float4*>(w + (long)(d+0)*4);
  const float4 w1 = *reinterpret_cast<const float4*>(w + (long)(d+1)*4);
  const float4 w2 = *reinterpret_cast<const float4*>(w + (long)(d+2)*4);
  const float4 w3 = *reinterpret_cast<const float4*>(w + (long)(d+3)*4);
  const float4 bv = *reinterpret_cast<const float4*>(bias + d);
  float a0 = bv.x, a1 = bv.y, a2 = bv.z, a3 = bv.w;
  const float wk0[4] = {w0.x, w0.y, w0.z, w0.w};
  const float wk1[4] = {w1.x, w1.y, w1.z, w1.w};
  const float wk2[4] = {w2.x, w2.y, w2.z, w2.w};
  const float wk3[4] = {w3.x, w3.y, w3.z, w3.w};
  #pragma unroll
  for (int k = 0; k < 4; ++k) {
    const int tt = t - 3 + k;
    if (tt >= 0) {
      const float4 xv = *reinterpret_cast<const float4*>(xin + ((long)(b * L + tt)) * DI + d);
      a0 = fmaf(wk0[k], xv.x, a0);
      a1 = fmaf(wk1[k], xv.y, a1);
      a2 = fmaf(wk2[k], xv.z, a2);
      a3 = fmaf(wk3[k], xv.w, a3);
    }
  }
  a0 = a0 / (1.f + expf(-a0));
  a1 = a1 / (1.f + expf(-a1));
  a2 = a2 / (1.f + expf(-a2));
  a3 = a3 / (1.f + expf(-a3));
  float4 o; o.x = a0; o.y = a1; o.z = a2; o.w = a3;
  *reinterpret_cast<float4*>(xc + (long)bt * DI + d) = o;
}

// ---------------- selective scan ----------------
// block = 256 threads = 16 channels x 16 states; grid = Bsz * DI/16
// y overwrites dty in place (row t store happens after row t/t+1 loads complete)
__global__ __launch_bounds__(256) void scan_kernel(
    float* __restrict__ dty,         // (ML, DI) f32: dt in, y out (aliased)
    const float* __restrict__ u,     // xc (ML, DI)
    const float* __restrict__ xdbl,  // (ML, 96): B at 64, C at 80
    const __hip_bfloat16* __restrict__ z, // (ML, DI) bf16
    const float* __restrict__ a_log, // (DI, 16) this layer
    const float* __restrict__ dpar)  // (DI)
{
  const int blk = blockIdx.x;
  const int b   = blk >> 7;            // / (DI/16)
  const int d0  = (blk & 127) << 4;
  const int tid = threadIdx.x;
  const int dl  = tid >> 4;
  const int s   = tid & 15;
  const int d   = d0 + dl;
  const float Aval = -expf(a_log[(long)d * DSTATE + s]);
  const float Dval = dpar[d];
  long row = (long)b * L;
  float dtv = dty[row * DI + d];
  float uv  = u [row * DI + d];
  float Bv  = xdbl[row * 96 + 64 + s];
  float Cv  = xdbl[row * 96 + 80 + s];
  float h = 0.f;
  for (int t = 0; t < L; ++t) {
    float dtn = 0.f, un = 0.f, Bn = 0.f, Cn = 0.f;
    if (t + 1 < L) {
      const long r2 = row + 1;
      dtn = dty[r2 * DI + d];
      un  = u [r2 * DI + d];
      Bn  = xdbl[r2 * 96 + 64 + s];
      Cn  = xdbl[r2 * 96 + 80 + s];
    }
    const float e = __expf(dtv * Aval);
    h = fmaf(e, h, dtv * uv * Bv);
    float p = h * Cv;
    p += __shfl_xor(p, 1);
    p += __shfl_xor(p, 2);
    p += __shfl_xor(p, 4);
    p += __shfl_xor(p, 8);
    if (s == 0) {
      const float zv = __bfloat162float(z[row * DI + d]);
      const float sg = zv / (1.f + __expf(-zv));
      dty[row * DI + d] = fmaf(uv, Dval, p) * sg;
    }
    dtv = dtn; uv = un; Bv = Bn; Cv = Cn; ++row;
  }
}

// ---------------- fused add-residual + rmsnorm ----------------
__global__ __launch_bounds__(256) void add_rmsnorm(
    const float* __restrict__ xin, const float* __restrict__ res,
    const float* __restrict__ w, float* __restrict__ out)
{
  const int row = blockIdx.x;
  const int tid = threadIdx.x;
  const long base = (long)row * D;
  float4 v = *reinterpret_cast<const float4*>(xin + base + tid * 4);
  const float4 r = *reinterpret_cast<const float4*>(res + base + tid * 4);
  v.x += r.x; v.y += r.y; v.z += r.z; v.w += r.w;
  float ss = v.x*v.x + v.y*v.y + v.z*v.z + v.w*v.w;
  #pragma unroll
  for (int m = 1; m < 64; m <<= 1) ss += __shfl_xor(ss, m);
  __shared__ float red[4];
  if ((tid & 63) == 0) red[tid >> 6] = ss;
  __syncthreads();
  const float tot = red[0] + red[1] + red[2] + red[3];
  const float scale = rsqrtf(tot * (1.f / (float)D) + 1.1920929e-07f);
  const float4 wv = *reinterpret_cast<const float4*>(w + tid * 4);
  float4 o;
  o.x = v.x * scale * wv.x;
  o.y = v.y * scale * wv.y;
  o.z = v.z * scale * wv.z;
  o.w = v.w * scale * wv.w;
  *reinterpret_cast<float4*>(out + base + tid * 4) = o;
}

} // namespace

extern "C" void kernel_launch(void* const* d_in, const int* in_sizes, int n_in,
                              void* d_out, int out_size, void* d_ws, size_t ws_size,
                              hipStream_t stream)
{
  const float* x0     = (const float*)d_in[0];
  const float* in_w   = (const float*)d_in[1];
  const float* conv_w = (const float*)d_in[2];
  const float* conv_b = (const float*)d_in[3];
  const float* xp_w   = (const float*)d_in[4];
  const float* dtp_w  = (const float*)d_in[5];
  const float* dtp_b  = (const float*)d_in[6];
  const float* a_log  = (const float*)d_in[7];
  const float* d_par  = (const float*)d_in[8];
  const float* out_w  = (const float*)d_in[9];
  const float* w1     = (const float*)d_in[10];
  const float* b1     = (const float*)d_in[11];
  const float* w2     = (const float*)d_in[12];
  const float* b2     = (const float*)d_in[13];
  const float* ln_w   = (const float*)d_in[14];
  const float* ln2_w  = (const float*)d_in[15];
  float* out = (float*)d_out;

  // ---- workspace layout: 224 MiB total (ws assumed >= 256 MiB) ----
  // bufA f32 ML*2048: x_in -> xdbl -> mo | t2
  // bufB bf16 ML*2048: z
  // bufC f32 ML*2048: xc -> hm
  // bufD f32 ML*2048: dt -> y (aliased in scan)
  char* ws = (char*)d_ws;
  float*          bufA = (float*)ws;                                  // 64 MiB
  __hip_bfloat16* bufB = (__hip_bfloat16*)(ws + (size_t)ML*2048*4);   // 32 MiB
  float*          bufC = (float*)(ws + (size_t)ML*2048*6);            // 64 MiB
  float*          bufD = (float*)(ws + (size_t)ML*2048*10);           // 64 MiB

  float*          xin  = bufA;
  float*          xdbl = bufA;
  float*          mo   = bufA;
  float*          t2   = bufA + (long)ML * 1024;
  __hip_bfloat16* zb   = bufB;
  float*          xc   = bufC;
  float*          hm   = bufC;
  float*          dty  = bufD;

  const dim3 blk(256);
  const float* xcur = x0;
  for (int layer = 0; layer < 2; ++layer) {
    const long lo = (long)layer;
    const float* Win = in_w + lo * 2 * DI * D;
    // 1a. x_in = xcur @ in_proj[0:2048]^T          (N=2048, K=1024)
    gemm_bt<0,false,false><<<dim3(DI/64, ML/128), blk, 0, stream>>>(
        xcur, D, Win, nullptr, xin, DI, DI, D);
    // 1b. z = xcur @ in_proj[2048:4096]^T  (bf16)  (N=2048, K=1024)
    gemm_bt<0,false,true><<<dim3(DI/64, ML/128), blk, 0, stream>>>(
        xcur, D, Win + (long)DI * D, nullptr, zb, DI, DI, D);
    // 2. xc = silu(causal_conv(x_in))
    conv_silu<<<dim3((long)ML*DI/4/256), blk, 0, stream>>>(
        xin, conv_w + lo*DI*4, conv_b + lo*DI, xc);
    // 3. xdbl = xc @ x_proj^T                      (N=96, K=2048) -> bufA
    gemm_bt<0,false,false><<<dim3(2, ML/128), blk, 0, stream>>>(
        xc, DI, xp_w + lo*96*DI, nullptr, xdbl, 96, 96, DI);
    // 4. dt = softplus(xdbl[:,:64] @ dt_proj^T + b) (N=2048, K=64) -> bufD
    gemm_bt<3,true,false><<<dim3(DI/64, ML/128), blk, 0, stream>>>(
        xdbl, 96, dtp_w + lo*DI*DTR, dtp_b + lo*DI, dty, DI, DI, DTR);
    // 5. selective scan (+ u*D, * silu(z)); y overwrites dt in bufD
    scan_kernel<<<dim3(Bsz*(DI/16)), blk, 0, stream>>>(
        dty, xc, xdbl, zb, a_log + lo*DI*DSTATE, d_par + lo*DI);
    // 6. mo = y @ out_proj^T                       (N=1024, K=2048) -> bufA
    gemm_bt<0,false,false><<<dim3(D/64, ML/128), blk, 0, stream>>>(
        dty, DI, out_w + lo*D*DI, nullptr, mo, D, D, DI);
    // 7. hm = gelu(mo @ w1^T + b1)                 (N=2048, K=1024) -> bufC
    gemm_bt<2,true,false><<<dim3(2*D/64, ML/128), blk, 0, stream>>>(
        mo, D, w1, b1, hm, 2*D, 2*D, D);
    // 8. t2 = gelu(hm @ w2^T + b2)                 (N=1024, K=2048) -> bufA hi
    gemm_bt<2,true,false><<<dim3(D/64, ML/128), blk, 0, stream>>>(
        hm, 2*D, w2, b2, t2, D, D, 2*D);
    // 9. x = rmsnorm(t2 + residual)
    add_rmsnorm<<<dim3(ML), blk, 0, stream>>>(t2, xcur, ln_w, out);
    xcur = out;
  }
  // final: rmsnorm(x + residual2)
  add_rmsnorm<<<dim3(ML), blk, 0, stream>>>(out, x0, ln2_w, out);
}

// Round 3
// 5676.334 us; speedup vs baseline: 1.5039x; 1.5039x over previous
//
#include <hip/hip_runtime.h>
#include <hip/hip_bf16.h>
#include <math.h>

namespace {

constexpr int Bsz = 4;
constexpr int L   = 2048;
constexpr int D   = 1024;
constexpr int DI  = 2048;
constexpr int DSTATE = 16;
constexpr int DTR = 64;
constexpr int ML  = Bsz * L; // 8192 rows
constexpr int NCH = 32;      // chunks per sequence
constexpr int CL  = 64;      // chunk length (NCH*CL == L)

// ---------------- activations ----------------
template<int ACT>
__device__ __forceinline__ float activate(float x) {
  if (ACT == 1) { return x / (1.f + expf(-x)); }                        // silu
  if (ACT == 2) { return 0.5f * x * (1.f + erff(x * 0.7071067811865475f)); } // exact gelu
  if (ACT == 3) { return (x > 20.f) ? x : log1pf(expf(x)); }            // softplus
  return x;
}

// ---------------- tiled f32 GEMM: C = act(A * W^T + bias) ----------------
template<int ACT, bool HAS_BIAS, bool BF16_OUT>
__global__ __launch_bounds__(256) void gemm_bt(
    const float* __restrict__ A, long lda,
    const float* __restrict__ W,
    const float* __restrict__ bias,
    void* __restrict__ Cp, long ldc,
    int N, int K)
{
  constexpr int BM = 128, BN = 64, BK = 16;
  __shared__ float As[BK][BM + 4];
  __shared__ float Ws[BK][BN + 4];
  const int bm = blockIdx.y * BM;
  const int bn = blockIdx.x * BN;
  const int tid = threadIdx.x;
  const int ty = tid >> 4, tx = tid & 15;
  float acc[8][4] = {};
  for (int k0 = 0; k0 < K; k0 += BK) {
    #pragma unroll
    for (int l = 0; l < 2; ++l) {
      const int id = tid + l * 256;
      const int m  = id >> 2;
      const int kq = id & 3;
      const float4 v = *reinterpret_cast<const float4*>(A + (long)(bm + m) * lda + k0 + kq * 4);
      As[kq*4+0][m] = v.x; As[kq*4+1][m] = v.y; As[kq*4+2][m] = v.z; As[kq*4+3][m] = v.w;
    }
    {
      const int n  = tid >> 2;
      const int kq = tid & 3;
      float4 v = make_float4(0.f, 0.f, 0.f, 0.f);
      if (bn + n < N)
        v = *reinterpret_cast<const float4*>(W + (long)(bn + n) * K + k0 + kq * 4);
      Ws[kq*4+0][n] = v.x; Ws[kq*4+1][n] = v.y; Ws[kq*4+2][n] = v.z; Ws[kq*4+3][n] = v.w;
    }
    __syncthreads();
    #pragma unroll
    for (int kk = 0; kk < BK; ++kk) {
      float a[8], bb[4];
      #pragma unroll
      for (int i = 0; i < 8; ++i) a[i] = As[kk][ty*8 + i];
      #pragma unroll
      for (int j = 0; j < 4; ++j) bb[j] = Ws[kk][tx*4 + j];
      #pragma unroll
      for (int i = 0; i < 8; ++i)
        #pragma unroll
        for (int j = 0; j < 4; ++j)
          acc[i][j] = fmaf(a[i], bb[j], acc[i][j]);
    }
    __syncthreads();
  }
  const int n0 = bn + tx * 4;
  if (n0 < N) {
    #pragma unroll
    for (int i = 0; i < 8; ++i) {
      const int m = bm + ty * 8 + i;
      float vv[4];
      #pragma unroll
      for (int j = 0; j < 4; ++j) {
        float v = acc[i][j];
        if (HAS_BIAS) v += bias[n0 + j];
        vv[j] = activate<ACT>(v);
      }
      if (BF16_OUT) {
        __hip_bfloat16 h[4];
        #pragma unroll
        for (int j = 0; j < 4; ++j) h[j] = __float2bfloat16(vv[j]);
        *reinterpret_cast<ushort4*>((__hip_bfloat16*)Cp + (long)m * ldc + n0) =
            *reinterpret_cast<ushort4*>(h);
      } else {
        float4 o; o.x = vv[0]; o.y = vv[1]; o.z = vv[2]; o.w = vv[3];
        *reinterpret_cast<float4*>((float*)Cp + (long)m * ldc + n0) = o;
      }
    }
  }
}

// ---------------- depthwise causal conv (k=4) + silu ----------------
__global__ __launch_bounds__(256) void conv_silu(
    const float* __restrict__ xin,
    const float* __restrict__ w,     // (DI, 4)
    const float* __restrict__ bias,  // (DI)
    float* __restrict__ xc)
{
  const int idx = blockIdx.x * 256 + threadIdx.x;   // over ML*DI/4
  const int D4 = DI / 4;
  const int d  = (idx % D4) * 4;
  const int bt = idx / D4;           // 0..ML-1
  const int t  = bt & (L - 1);
  const int b  = bt >> 11;
  const float4 w0 = *reinterpret_cast<const float4*>(w + (long)(d+0)*4);
  const float4 w1 = *reinterpret_cast<const float4*>(w + (long)(d+1)*4);
  const float4 w2 = *reinterpret_cast<const float4*>(w + (long)(d+2)*4);
  const float4 w3 = *reinterpret_cast<const float4*>(w + (long)(d+3)*4);
  const float4 bv = *reinterpret_cast<const float4*>(bias + d);
  float a0 = bv.x, a1 = bv.y, a2 = bv.z, a3 = bv.w;
  const float wk0[4] = {w0.x, w0.y, w0.z, w0.w};
  const float wk1[4] = {w1.x, w1.y, w1.z, w1.w};
  const float wk2[4] = {w2.x, w2.y, w2.z, w2.w};
  const float wk3[4] = {w3.x, w3.y, w3.z, w3.w};
  #pragma unroll
  for (int k = 0; k < 4; ++k) {
    const int tt = t - 3 + k;
    if (tt >= 0) {
      const float4 xv = *reinterpret_cast<const float4*>(xin + ((long)(b * L + tt)) * DI + d);
      a0 = fmaf(wk0[k], xv.x, a0);
      a1 = fmaf(wk1[k], xv.y, a1);
      a2 = fmaf(wk2[k], xv.z, a2);
      a3 = fmaf(wk3[k], xv.w, a3);
    }
  }
  a0 = a0 / (1.f + expf(-a0));
  a1 = a1 / (1.f + expf(-a1));
  a2 = a2 / (1.f + expf(-a2));
  a3 = a3 / (1.f + expf(-a3));
  float4 o; o.x = a0; o.y = a1; o.z = a2; o.w = a3;
  *reinterpret_cast<float4*>(xc + (long)bt * DI + d) = o;
}

// ---------------- chunked selective scan ----------------
// P1: per (b,chunk,d) thread, 16 states in regs, h_start=0:
//     store chunk-local h_end[b][c][s][d] and sum_dt[b][c][d]
__global__ __launch_bounds__(256) void scan_p1(
    const float* __restrict__ dt,    // (ML, DI)
    const float* __restrict__ u,     // (ML, DI)
    const float* __restrict__ xdbl,  // (ML, 96): B at 64
    const float* __restrict__ a_log, // (DI, 16)
    float* __restrict__ hend,        // (Bsz, NCH, 16, DI)
    float* __restrict__ sdt)         // (Bsz, NCH, DI)
{
  const int bid = blockIdx.x;
  const int dg = bid & 7;            // DI/256
  const int c  = (bid >> 3) & (NCH - 1);
  const int b  = bid >> 8;
  const int d  = dg * 256 + threadIdx.x;
  float A[16];
  #pragma unroll
  for (int q = 0; q < 4; ++q) {
    const float4 al = *reinterpret_cast<const float4*>(a_log + (long)d * 16 + q * 4);
    A[q*4+0] = -__expf(al.x); A[q*4+1] = -__expf(al.y);
    A[q*4+2] = -__expf(al.z); A[q*4+3] = -__expf(al.w);
  }
  float h[16];
  #pragma unroll
  for (int s = 0; s < 16; ++s) h[s] = 0.f;
  float s_dt = 0.f;
  const long row0 = (long)b * L + (long)c * CL;
  for (int t = 0; t < CL; ++t) {
    const long row = row0 + t;
    const float dtv = dt[row * DI + d];
    const float uv  = u [row * DI + d];
    const float* bp = xdbl + row * 96 + 64;
    const float4 B0 = *reinterpret_cast<const float4*>(bp + 0);
    const float4 B1 = *reinterpret_cast<const float4*>(bp + 4);
    const float4 B2 = *reinterpret_cast<const float4*>(bp + 8);
    const float4 B3 = *reinterpret_cast<const float4*>(bp + 12);
    const float Bv[16] = {B0.x,B0.y,B0.z,B0.w, B1.x,B1.y,B1.z,B1.w,
                          B2.x,B2.y,B2.z,B2.w, B3.x,B3.y,B3.z,B3.w};
    s_dt += dtv;
    const float dtu = dtv * uv;
    #pragma unroll
    for (int s = 0; s < 16; ++s)
      h[s] = fmaf(__expf(dtv * A[s]), h[s], dtu * Bv[s]);
  }
  const long cb = (long)(b * NCH + c);
  #pragma unroll
  for (int s = 0; s < 16; ++s)
    hend[(cb * 16 + s) * DI + d] = h[s];
  sdt[cb * DI + d] = s_dt;
}

// P2: per (b,d,s): serial prefix over chunks; hend becomes h_init
__global__ __launch_bounds__(256) void scan_p2(
    float* __restrict__ hend,        // inout: local h_end -> h_init
    const float* __restrict__ sdt,
    const float* __restrict__ a_log)
{
  const long idx = (long)blockIdx.x * 256 + threadIdx.x; // over Bsz*16*DI
  const int d = idx & (DI - 1);
  const int s = (idx >> 11) & 15;
  const int b = idx >> 15;
  const float A = -__expf(a_log[(long)d * 16 + s]);
  float h = 0.f;
  for (int c = 0; c < NCH; ++c) {
    const long cb = (long)(b * NCH + c);
    const long off = (cb * 16 + s) * DI + d;
    const float hl = hend[off];
    const float sd = sdt[cb * DI + d];
    hend[off] = h;                     // h_init for chunk c
    h = fmaf(__expf(A * sd), h, hl);   // actual h_end of chunk c
  }
}

// P3: recompute with correct h_init; y = (sum h*C + u*D)*silu(z) overwrites dt
__global__ __launch_bounds__(256) void scan_p3(
    float* __restrict__ dty,         // (ML, DI): dt in, y out (in place)
    const float* __restrict__ u,
    const float* __restrict__ xdbl,  // B at 64, C at 80
    const __hip_bfloat16* __restrict__ z,
    const float* __restrict__ a_log,
    const float* __restrict__ dpar,
    const float* __restrict__ hinit) // (Bsz, NCH, 16, DI)
{
  const int bid = blockIdx.x;
  const int dg = bid & 7;
  const int c  = (bid >> 3) & (NCH - 1);
  const int b  = bid >> 8;
  const int d  = dg * 256 + threadIdx.x;
  float A[16];
  #pragma unroll
  for (int q = 0; q < 4; ++q) {
    const float4 al = *reinterpret_cast<const float4*>(a_log + (long)d * 16 + q * 4);
    A[q*4+0] = -__expf(al.x); A[q*4+1] = -__expf(al.y);
    A[q*4+2] = -__expf(al.z); A[q*4+3] = -__expf(al.w);
  }
  const float Dv = dpar[d];
  const long cb = (long)(b * NCH + c);
  float h[16];
  #pragma unroll
  for (int s = 0; s < 16; ++s)
    h[s] = hinit[(cb * 16 + s) * DI + d];
  const long row0 = (long)b * L + (long)c * CL;
  for (int t = 0; t < CL; ++t) {
    const long row = row0 + t;
    const float dtv = dty[row * DI + d];
    const float uv  = u [row * DI + d];
    const float* bp = xdbl + row * 96 + 64;
    const float4 B0 = *reinterpret_cast<const float4*>(bp + 0);
    const float4 B1 = *reinterpret_cast<const float4*>(bp + 4);
    const float4 B2 = *reinterpret_cast<const float4*>(bp + 8);
    const float4 B3 = *reinterpret_cast<const float4*>(bp + 12);
    const float4 C0 = *reinterpret_cast<const float4*>(bp + 16);
    const float4 C1 = *reinterpret_cast<const float4*>(bp + 20);
    const float4 C2 = *reinterpret_cast<const float4*>(bp + 24);
    const float4 C3 = *reinterpret_cast<const float4*>(bp + 28);
    const float Bv[16] = {B0.x,B0.y,B0.z,B0.w, B1.x,B1.y,B1.z,B1.w,
                          B2.x,B2.y,B2.z,B2.w, B3.x,B3.y,B3.z,B3.w};
    const float Cv[16] = {C0.x,C0.y,C0.z,C0.w, C1.x,C1.y,C1.z,C1.w,
                          C2.x,C2.y,C2.z,C2.w, C3.x,C3.y,C3.z,C3.w};
    const float dtu = dtv * uv;
    float y = 0.f;
    #pragma unroll
    for (int s = 0; s < 16; ++s) {
      h[s] = fmaf(__expf(dtv * A[s]), h[s], dtu * Bv[s]);
      y = fmaf(h[s], Cv[s], y);
    }
    const float zv = __bfloat162float(z[row * DI + d]);
    const float sg = zv / (1.f + __expf(-zv));
    dty[row * DI + d] = fmaf(uv, Dv, y) * sg;
  }
}

// ---------------- fused add-residual + rmsnorm ----------------
__global__ __launch_bounds__(256) void add_rmsnorm(
    const float* __restrict__ xin, const float* __restrict__ res,
    const float* __restrict__ w, float* __restrict__ out)
{
  const int row = blockIdx.x;
  const int tid = threadIdx.x;
  const long base = (long)row * D;
  float4 v = *reinterpret_cast<const float4*>(xin + base + tid * 4);
  const float4 r = *reinterpret_cast<const float4*>(res + base + tid * 4);
  v.x += r.x; v.y += r.y; v.z += r.z; v.w += r.w;
  float ss = v.x*v.x + v.y*v.y + v.z*v.z + v.w*v.w;
  #pragma unroll
  for (int m = 1; m < 64; m <<= 1) ss += __shfl_xor(ss, m);
  __shared__ float red[4];
  if ((tid & 63) == 0) red[tid >> 6] = ss;
  __syncthreads();
  const float tot = red[0] + red[1] + red[2] + red[3];
  const float scale = rsqrtf(tot * (1.f / (float)D) + 1.1920929e-07f);
  const float4 wv = *reinterpret_cast<const float4*>(w + tid * 4);
  float4 o;
  o.x = v.x * scale * wv.x;
  o.y = v.y * scale * wv.y;
  o.z = v.z * scale * wv.z;
  o.w = v.w * scale * wv.w;
  *reinterpret_cast<float4*>(out + base + tid * 4) = o;
}

} // namespace

extern "C" void kernel_launch(void* const* d_in, const int* in_sizes, int n_in,
                              void* d_out, int out_size, void* d_ws, size_t ws_size,
                              hipStream_t stream)
{
  const float* x0     = (const float*)d_in[0];
  const float* in_w   = (const float*)d_in[1];
  const float* conv_w = (const float*)d_in[2];
  const float* conv_b = (const float*)d_in[3];
  const float* xp_w   = (const float*)d_in[4];
  const float* dtp_w  = (const float*)d_in[5];
  const float* dtp_b  = (const float*)d_in[6];
  const float* a_log  = (const float*)d_in[7];
  const float* d_par  = (const float*)d_in[8];
  const float* out_w  = (const float*)d_in[9];
  const float* w1     = (const float*)d_in[10];
  const float* b1     = (const float*)d_in[11];
  const float* w2     = (const float*)d_in[12];
  const float* b2     = (const float*)d_in[13];
  const float* ln_w   = (const float*)d_in[14];
  const float* ln2_w  = (const float*)d_in[15];
  float* out = (float*)d_out;

  // ---- workspace layout: 224 MiB total ----
  // bufA f32 ML*2048: x_in -> xdbl(3.1MB) + scan scratch -> mo | t2
  // bufB bf16 ML*2048: z
  // bufC f32 ML*2048: xc -> hm
  // bufD f32 ML*2048: dt -> y (in place)
  char* ws = (char*)d_ws;
  float*          bufA = (float*)ws;                                  // 64 MiB
  __hip_bfloat16* bufB = (__hip_bfloat16*)(ws + (size_t)ML*2048*4);   // 32 MiB
  float*          bufC = (float*)(ws + (size_t)ML*2048*6);            // 64 MiB
  float*          bufD = (float*)(ws + (size_t)ML*2048*10);           // 64 MiB

  float*          xin  = bufA;
  float*          xdbl = bufA;                    // ML*96 = 3.1 MB
  float*          sdtb = (float*)(ws + (4UL  << 20));  // 1.05 MB  (inside bufA)
  float*          hendb= (float*)(ws + (6UL  << 20));  // 16.8 MB  (inside bufA)
  float*          mo   = bufA;
  float*          t2   = bufA + (long)ML * 1024;
  __hip_bfloat16* zb   = bufB;
  float*          xc   = bufC;
  float*          hm   = bufC;
  float*          dty  = bufD;

  const dim3 blk(256);
  const float* xcur = x0;
  for (int layer = 0; layer < 2; ++layer) {
    const long lo = (long)layer;
    const float* Win = in_w + lo * 2 * DI * D;
    // 1a. x_in = xcur @ in_proj[0:2048]^T          (N=2048, K=1024)
    gemm_bt<0,false,false><<<dim3(DI/64, ML/128), blk, 0, stream>>>(
        xcur, D, Win, nullptr, xin, DI, DI, D);
    // 1b. z = xcur @ in_proj[2048:4096]^T  (bf16)
    gemm_bt<0,false,true><<<dim3(DI/64, ML/128), blk, 0, stream>>>(
        xcur, D, Win + (long)DI * D, nullptr, zb, DI, DI, D);
    // 2. xc = silu(causal_conv(x_in))
    conv_silu<<<dim3((long)ML*DI/4/256), blk, 0, stream>>>(
        xin, conv_w + lo*DI*4, conv_b + lo*DI, xc);
    // 3. xdbl = xc @ x_proj^T                      (N=96, K=2048)
    gemm_bt<0,false,false><<<dim3(2, ML/128), blk, 0, stream>>>(
        xc, DI, xp_w + lo*96*DI, nullptr, xdbl, 96, 96, DI);
    // 4. dt = softplus(xdbl[:,:64] @ dt_proj^T + b) (N=2048, K=64)
    gemm_bt<3,true,false><<<dim3(DI/64, ML/128), blk, 0, stream>>>(
        xdbl, 96, dtp_w + lo*DI*DTR, dtp_b + lo*DI, dty, DI, DI, DTR);
    // 5. chunked selective scan; y overwrites dt in bufD
    scan_p1<<<dim3(Bsz*NCH*(DI/256)), blk, 0, stream>>>(
        dty, xc, xdbl, a_log + lo*DI*DSTATE, hendb, sdtb);
    scan_p2<<<dim3(Bsz*DSTATE*DI/256), blk, 0, stream>>>(
        hendb, sdtb, a_log + lo*DI*DSTATE);
    scan_p3<<<dim3(Bsz*NCH*(DI/256)), blk, 0, stream>>>(
        dty, xc, xdbl, zb, a_log + lo*DI*DSTATE, d_par + lo*DI, hendb);
    // 6. mo = y @ out_proj^T                       (N=1024, K=2048)
    gemm_bt<0,false,false><<<dim3(D/64, ML/128), blk, 0, stream>>>(
        dty, DI, out_w + lo*D*DI, nullptr, mo, D, D, DI);
    // 7. hm = gelu(mo @ w1^T + b1)                 (N=2048, K=1024)
    gemm_bt<2,true,false><<<dim3(2*D/64, ML/128), blk, 0, stream>>>(
        mo, D, w1, b1, hm, 2*D, 2*D, D);
    // 8. t2 = gelu(hm @ w2^T + b2)                 (N=1024, K=2048)
    gemm_bt<2,true,false><<<dim3(D/64, ML/128), blk, 0, stream>>>(
        hm, 2*D, w2, b2, t2, D, D, 2*D);
    // 9. x = rmsnorm(t2 + residual)
    add_rmsnorm<<<dim3(ML), blk, 0, stream>>>(t2, xcur, ln_w, out);
    xcur = out;
  }
  // final: rmsnorm(x + residual2)
  add_rmsnorm<<<dim3(ML), blk, 0, stream>>>(out, x0, ln2_w, out);
}

// Round 4
// 1659.922 us; speedup vs baseline: 5.1428x; 3.4196x over previous
//
#include <hip/hip_runtime.h>
#include <math.h>

namespace {

constexpr int Bsz = 4;
constexpr int L   = 2048;
constexpr int D   = 1024;
constexpr int DI  = 2048;
constexpr int DSTATE = 16;
constexpr int DTR = 64;
constexpr int ML  = Bsz * L; // 8192 rows
constexpr int NCH = 32;      // chunks per sequence
constexpr int CL  = 64;      // chunk length

typedef __attribute__((ext_vector_type(8))) short bfrag;   // 8 bf16 (4 VGPRs)
typedef __attribute__((ext_vector_type(4))) float f32x4;

// ---- bf16 bit helpers (RNE) ----
__device__ __forceinline__ unsigned short f2b(float f) {
  union { float f; unsigned int u; } c; c.f = f;
  unsigned int u = c.u;
  unsigned int r = (u + 0x7fffu + ((u >> 16) & 1u)) >> 16;
  return (unsigned short)r;
}
__device__ __forceinline__ float b2f(unsigned short h) {
  union { unsigned int u; float f; } c; c.u = ((unsigned int)h) << 16;
  return c.f;
}

// ---- async global->LDS 16B ----
__device__ __forceinline__ void async16(const void* g, void* l) {
  __builtin_amdgcn_global_load_lds(
      (const __attribute__((address_space(1))) void*)g,
      (__attribute__((address_space(3))) void*)l, 16, 0, 0);
}

// ---------------- activations ----------------
template<int ACT>
__device__ __forceinline__ float activate(float x) {
  if (ACT == 1) { return x / (1.f + expf(-x)); }
  if (ACT == 2) { return 0.5f * x * (1.f + erff(x * 0.7071067811865475f)); }
  if (ACT == 3) { return (x > 20.f) ? x : log1pf(expf(x)); }
  return x;
}

// ---------------- bf16 MFMA GEMM: C(bf16) = act(A * W^T + bias) ----------------
// A: (M x K) bf16 row-major stride lda; W: (N x K) bf16 row-major stride K.
// 128x128 tile, BK=32, 4 waves (2x2), mfma_f32_16x16x32_bf16.
template<int ACT, bool HAS_BIAS>
__global__ __launch_bounds__(256) void gemm_mfma(
    const unsigned short* __restrict__ A, long lda,
    const unsigned short* __restrict__ W, long ldw,
    const float* __restrict__ bias,
    unsigned short* __restrict__ C, long ldc,
    int K)
{
  __shared__ unsigned short As[128 * 32];
  __shared__ unsigned short Bs[128 * 32];
  const int tid  = threadIdx.x;
  const int lane = tid & 63;
  const int w    = tid >> 6;
  const int wr   = w >> 1, wc = w & 1;
  const long bm = (long)blockIdx.y * 128;
  const long bn = (long)blockIdx.x * 128;

  // staging: thread tid loads 8 bf16 (16B); tile row = tid/4 (+64), col = (tid&3)*8
  const int srow = tid >> 2;
  const int scol = (tid & 3) * 8;
  const unsigned short* ga0 = A + (bm + srow)      * lda + scol;
  const unsigned short* ga1 = A + (bm + 64 + srow) * lda + scol;
  const unsigned short* gb0 = W + (bn + srow)      * ldw + scol;
  const unsigned short* gb1 = W + (bn + 64 + srow) * ldw + scol;
  char* lA = (char*)As;
  char* lB = (char*)Bs;
  const int loff = tid * 16;

  // fragment read geometry: row = lane&15, k-offset = (lane>>4)*8
  const int frow = lane & 15;
  const int fko  = (lane >> 4) * 8;

  f32x4 acc[4][4];
  #pragma unroll
  for (int m = 0; m < 4; ++m)
    #pragma unroll
    for (int n = 0; n < 4; ++n)
      acc[m][n] = (f32x4){0.f, 0.f, 0.f, 0.f};

  for (int k0 = 0; k0 < K; k0 += 32) {
    __syncthreads();
    async16(ga0 + k0, lA + loff);
    async16(ga1 + k0, lA + 4096 + loff);
    async16(gb0 + k0, lB + loff);
    async16(gb1 + k0, lB + 4096 + loff);
    __syncthreads();   // drains vmcnt before barrier
    bfrag a[4], b[4];
    #pragma unroll
    for (int m = 0; m < 4; ++m)
      a[m] = *reinterpret_cast<const bfrag*>(&As[(wr*64 + m*16 + frow)*32 + fko]);
    #pragma unroll
    for (int n = 0; n < 4; ++n)
      b[n] = *reinterpret_cast<const bfrag*>(&Bs[(wc*64 + n*16 + frow)*32 + fko]);
    #pragma unroll
    for (int m = 0; m < 4; ++m)
      #pragma unroll
      for (int n = 0; n < 4; ++n)
        acc[m][n] = __builtin_amdgcn_mfma_f32_16x16x32_bf16(a[m], b[n], acc[m][n], 0, 0, 0);
  }

  // epilogue: D col = lane&15, row = (lane>>4)*4 + j
  #pragma unroll
  for (int n = 0; n < 4; ++n) {
    const long col = bn + wc*64 + n*16 + frow;
    const float bv = HAS_BIAS ? bias[col] : 0.f;
    #pragma unroll
    for (int m = 0; m < 4; ++m) {
      const long row = bm + wr*64 + m*16 + (lane >> 4) * 4;
      #pragma unroll
      for (int j = 0; j < 4; ++j) {
        float v = acc[m][n][j] + bv;
        v = activate<ACT>(v);
        C[(row + j) * ldc + col] = f2b(v);
      }
    }
  }
}

// ---------------- tiled f32 SGEMM (small GEMMs): C = act(A * W^T + bias) ----
template<int ACT, bool HAS_BIAS, bool BF16_OUT, bool BF16_IN>
__global__ __launch_bounds__(256) void gemm_bt(
    const void* __restrict__ Ap, long lda,
    const float* __restrict__ W,
    const float* __restrict__ bias,
    void* __restrict__ Cp, long ldc,
    int N, int K)
{
  constexpr int BM = 128, BN = 64, BK = 16;
  __shared__ float As[BK][BM + 4];
  __shared__ float Ws[BK][BN + 4];
  const int bm = blockIdx.y * BM;
  const int bn = blockIdx.x * BN;
  const int tid = threadIdx.x;
  const int ty = tid >> 4, tx = tid & 15;
  float acc[8][4] = {};
  for (int k0 = 0; k0 < K; k0 += BK) {
    #pragma unroll
    for (int l = 0; l < 2; ++l) {
      const int id = tid + l * 256;
      const int m  = id >> 2;
      const int kq = id & 3;
      if (BF16_IN) {
        const unsigned short* Ab = (const unsigned short*)Ap;
        const ushort4 v = *reinterpret_cast<const ushort4*>(Ab + (long)(bm + m) * lda + k0 + kq * 4);
        As[kq*4+0][m] = b2f(v.x); As[kq*4+1][m] = b2f(v.y);
        As[kq*4+2][m] = b2f(v.z); As[kq*4+3][m] = b2f(v.w);
      } else {
        const float* Af = (const float*)Ap;
        const float4 v = *reinterpret_cast<const float4*>(Af + (long)(bm + m) * lda + k0 + kq * 4);
        As[kq*4+0][m] = v.x; As[kq*4+1][m] = v.y; As[kq*4+2][m] = v.z; As[kq*4+3][m] = v.w;
      }
    }
    {
      const int n  = tid >> 2;
      const int kq = tid & 3;
      float4 v = make_float4(0.f, 0.f, 0.f, 0.f);
      if (bn + n < N)
        v = *reinterpret_cast<const float4*>(W + (long)(bn + n) * K + k0 + kq * 4);
      Ws[kq*4+0][n] = v.x; Ws[kq*4+1][n] = v.y; Ws[kq*4+2][n] = v.z; Ws[kq*4+3][n] = v.w;
    }
    __syncthreads();
    #pragma unroll
    for (int kk = 0; kk < BK; ++kk) {
      float a[8], bb[4];
      #pragma unroll
      for (int i = 0; i < 8; ++i) a[i] = As[kk][ty*8 + i];
      #pragma unroll
      for (int j = 0; j < 4; ++j) bb[j] = Ws[kk][tx*4 + j];
      #pragma unroll
      for (int i = 0; i < 8; ++i)
        #pragma unroll
        for (int j = 0; j < 4; ++j)
          acc[i][j] = fmaf(a[i], bb[j], acc[i][j]);
    }
    __syncthreads();
  }
  const int n0 = bn + tx * 4;
  if (n0 < N) {
    #pragma unroll
    for (int i = 0; i < 8; ++i) {
      const int m = bm + ty * 8 + i;
      float vv[4];
      #pragma unroll
      for (int j = 0; j < 4; ++j) {
        float v = acc[i][j];
        if (HAS_BIAS) v += bias[n0 + j];
        vv[j] = activate<ACT>(v);
      }
      if (BF16_OUT) {
        ushort4 o; o.x = f2b(vv[0]); o.y = f2b(vv[1]); o.z = f2b(vv[2]); o.w = f2b(vv[3]);
        *reinterpret_cast<ushort4*>((unsigned short*)Cp + (long)m * ldc + n0) = o;
      } else {
        float4 o; o.x = vv[0]; o.y = vv[1]; o.z = vv[2]; o.w = vv[3];
        *reinterpret_cast<float4*>((float*)Cp + (long)m * ldc + n0) = o;
      }
    }
  }
}

// ---------------- f32 -> bf16 convert ----------------
__global__ __launch_bounds__(256) void cvt_bf16(
    const float* __restrict__ in, unsigned short* __restrict__ out, long n4)
{
  const long i = (long)blockIdx.x * 256 + threadIdx.x;
  if (i < n4) {
    const float4 v = reinterpret_cast<const float4*>(in)[i];
    ushort4 o; o.x = f2b(v.x); o.y = f2b(v.y); o.z = f2b(v.z); o.w = f2b(v.w);
    reinterpret_cast<ushort4*>(out)[i] = o;
  }
}

// ---------------- depthwise causal conv (k=4) + silu, bf16 in/out ----------------
__global__ __launch_bounds__(256) void conv_silu(
    const unsigned short* __restrict__ xin,
    const float* __restrict__ w,     // (DI, 4) f32
    const float* __restrict__ bias,  // (DI) f32
    unsigned short* __restrict__ xc)
{
  const int idx = blockIdx.x * 256 + threadIdx.x;
  const int D4 = DI / 4;
  const int d  = (idx % D4) * 4;
  const int bt = idx / D4;
  const int t  = bt & (L - 1);
  const int b  = bt >> 11;
  const float4 w0 = *reinterpret_cast<const float4*>(w + (long)(d+0)*4);
  const float4 w1 = *reinterpret_cast<const float4*>(w + (long)(d+1)*4);
  const float4 w2 = *reinterpret_cast<const float4*>(w + (long)(d+2)*4);
  const float4 w3 = *reinterpret_cast<const float4*>(w + (long)(d+3)*4);
  const float4 bv = *reinterpret_cast<const float4*>(bias + d);
  float a0 = bv.x, a1 = bv.y, a2 = bv.z, a3 = bv.w;
  const float wk0[4] = {w0.x, w0.y, w0.z, w0.w};
  const float wk1[4] = {w1.x, w1.y, w1.z, w1.w};
  const float wk2[4] = {w2.x, w2.y, w2.z, w2.w};
  const float wk3[4] = {w3.x, w3.y, w3.z, w3.w};
  #pragma unroll
  for (int k = 0; k < 4; ++k) {
    const int tt = t - 3 + k;
    if (tt >= 0) {
      const ushort4 xv = *reinterpret_cast<const ushort4*>(xin + ((long)(b * L + tt)) * DI + d);
      a0 = fmaf(wk0[k], b2f(xv.x), a0);
      a1 = fmaf(wk1[k], b2f(xv.y), a1);
      a2 = fmaf(wk2[k], b2f(xv.z), a2);
      a3 = fmaf(wk3[k], b2f(xv.w), a3);
    }
  }
  a0 = a0 / (1.f + expf(-a0));
  a1 = a1 / (1.f + expf(-a1));
  a2 = a2 / (1.f + expf(-a2));
  a3 = a3 / (1.f + expf(-a3));
  ushort4 o; o.x = f2b(a0); o.y = f2b(a1); o.z = f2b(a2); o.w = f2b(a3);
  *reinterpret_cast<ushort4*>(xc + (long)bt * DI + d) = o;
}

// ---------------- chunked selective scan ----------------
__global__ __launch_bounds__(256) void scan_p1(
    const unsigned short* __restrict__ dt,   // (ML, DI) bf16
    const unsigned short* __restrict__ u,    // (ML, DI) bf16
    const float* __restrict__ xdbl,          // (ML, 96): B at 64
    const float* __restrict__ a_log,         // (DI, 16)
    float* __restrict__ hend,                // (Bsz, NCH, 16, DI)
    float* __restrict__ sdt)                 // (Bsz, NCH, DI)
{
  const int bid = blockIdx.x;
  const int dg = bid & 7;
  const int c  = (bid >> 3) & (NCH - 1);
  const int b  = bid >> 8;
  const int d  = dg * 256 + threadIdx.x;
  float A[16];
  #pragma unroll
  for (int q = 0; q < 4; ++q) {
    const float4 al = *reinterpret_cast<const float4*>(a_log + (long)d * 16 + q * 4);
    A[q*4+0] = -__expf(al.x); A[q*4+1] = -__expf(al.y);
    A[q*4+2] = -__expf(al.z); A[q*4+3] = -__expf(al.w);
  }
  float h[16];
  #pragma unroll
  for (int s = 0; s < 16; ++s) h[s] = 0.f;
  float s_dt = 0.f;
  const long row0 = (long)b * L + (long)c * CL;
  for (int t = 0; t < CL; ++t) {
    const long row = row0 + t;
    const float dtv = b2f(dt[row * DI + d]);
    const float uv  = b2f(u [row * DI + d]);
    const float* bp = xdbl + row * 96 + 64;
    const float4 B0 = *reinterpret_cast<const float4*>(bp + 0);
    const float4 B1 = *reinterpret_cast<const float4*>(bp + 4);
    const float4 B2 = *reinterpret_cast<const float4*>(bp + 8);
    const float4 B3 = *reinterpret_cast<const float4*>(bp + 12);
    const float Bv[16] = {B0.x,B0.y,B0.z,B0.w, B1.x,B1.y,B1.z,B1.w,
                          B2.x,B2.y,B2.z,B2.w, B3.x,B3.y,B3.z,B3.w};
    s_dt += dtv;
    const float dtu = dtv * uv;
    #pragma unroll
    for (int s = 0; s < 16; ++s)
      h[s] = fmaf(__expf(dtv * A[s]), h[s], dtu * Bv[s]);
  }
  const long cb = (long)(b * NCH + c);
  #pragma unroll
  for (int s = 0; s < 16; ++s)
    hend[(cb * 16 + s) * DI + d] = h[s];
  sdt[cb * DI + d] = s_dt;
}

__global__ __launch_bounds__(256) void scan_p2(
    float* __restrict__ hend,
    const float* __restrict__ sdt,
    const float* __restrict__ a_log)
{
  const long idx = (long)blockIdx.x * 256 + threadIdx.x;
  const int d = idx & (DI - 1);
  const int s = (idx >> 11) & 15;
  const int b = idx >> 15;
  const float A = -__expf(a_log[(long)d * 16 + s]);
  float h = 0.f;
  for (int c = 0; c < NCH; ++c) {
    const long cb = (long)(b * NCH + c);
    const long off = (cb * 16 + s) * DI + d;
    const float hl = hend[off];
    const float sd = sdt[cb * DI + d];
    hend[off] = h;
    h = fmaf(__expf(A * sd), h, hl);
  }
}

__global__ __launch_bounds__(256) void scan_p3(
    const unsigned short* __restrict__ dt,
    const unsigned short* __restrict__ u,
    const float* __restrict__ xdbl,          // B at 64, C at 80
    const unsigned short* __restrict__ z,
    const float* __restrict__ a_log,
    const float* __restrict__ dpar,
    const float* __restrict__ hinit,
    unsigned short* __restrict__ y)
{
  const int bid = blockIdx.x;
  const int dg = bid & 7;
  const int c  = (bid >> 3) & (NCH - 1);
  const int b  = bid >> 8;
  const int d  = dg * 256 + threadIdx.x;
  float A[16];
  #pragma unroll
  for (int q = 0; q < 4; ++q) {
    const float4 al = *reinterpret_cast<const float4*>(a_log + (long)d * 16 + q * 4);
    A[q*4+0] = -__expf(al.x); A[q*4+1] = -__expf(al.y);
    A[q*4+2] = -__expf(al.z); A[q*4+3] = -__expf(al.w);
  }
  const float Dv = dpar[d];
  const long cb = (long)(b * NCH + c);
  float h[16];
  #pragma unroll
  for (int s = 0; s < 16; ++s)
    h[s] = hinit[(cb * 16 + s) * DI + d];
  const long row0 = (long)b * L + (long)c * CL;
  for (int t = 0; t < CL; ++t) {
    const long row = row0 + t;
    const float dtv = b2f(dt[row * DI + d]);
    const float uv  = b2f(u [row * DI + d]);
    const float* bp = xdbl + row * 96 + 64;
    const float4 B0 = *reinterpret_cast<const float4*>(bp + 0);
    const float4 B1 = *reinterpret_cast<const float4*>(bp + 4);
    const float4 B2 = *reinterpret_cast<const float4*>(bp + 8);
    const float4 B3 = *reinterpret_cast<const float4*>(bp + 12);
    const float4 C0 = *reinterpret_cast<const float4*>(bp + 16);
    const float4 C1 = *reinterpret_cast<const float4*>(bp + 20);
    const float4 C2 = *reinterpret_cast<const float4*>(bp + 24);
    const float4 C3 = *reinterpret_cast<const float4*>(bp + 28);
    const float Bv[16] = {B0.x,B0.y,B0.z,B0.w, B1.x,B1.y,B1.z,B1.w,
                          B2.x,B2.y,B2.z,B2.w, B3.x,B3.y,B3.z,B3.w};
    const float Cv[16] = {C0.x,C0.y,C0.z,C0.w, C1.x,C1.y,C1.z,C1.w,
                          C2.x,C2.y,C2.z,C2.w, C3.x,C3.y,C3.z,C3.w};
    const float dtu = dtv * uv;
    float yv = 0.f;
    #pragma unroll
    for (int s = 0; s < 16; ++s) {
      h[s] = fmaf(__expf(dtv * A[s]), h[s], dtu * Bv[s]);
      yv = fmaf(h[s], Cv[s], yv);
    }
    const float zv = b2f(z[row * DI + d]);
    const float sg = zv / (1.f + __expf(-zv));
    y[row * DI + d] = f2b(fmaf(uv, Dv, yv) * sg);
  }
}

// ---------------- fused add-residual + rmsnorm ----------------
// BIN: xin is bf16; WBF: also emit bf16 copy of the normalized output
template<bool BIN, bool WBF>
__global__ __launch_bounds__(256) void add_rmsnorm(
    const void* __restrict__ xinp, const float* __restrict__ res,
    const float* __restrict__ w, float* __restrict__ out,
    unsigned short* __restrict__ xb)
{
  const int row = blockIdx.x;
  const int tid = threadIdx.x;
  const long base = (long)row * D;
  float4 v;
  if (BIN) {
    const ushort4 t = *reinterpret_cast<const ushort4*>((const unsigned short*)xinp + base + tid * 4);
    v.x = b2f(t.x); v.y = b2f(t.y); v.z = b2f(t.z); v.w = b2f(t.w);
  } else {
    v = *reinterpret_cast<const float4*>((const float*)xinp + base + tid * 4);
  }
  const float4 r = *reinterpret_cast<const float4*>(res + base + tid * 4);
  v.x += r.x; v.y += r.y; v.z += r.z; v.w += r.w;
  float ss = v.x*v.x + v.y*v.y + v.z*v.z + v.w*v.w;
  #pragma unroll
  for (int m = 1; m < 64; m <<= 1) ss += __shfl_xor(ss, m);
  __shared__ float red[4];
  if ((tid & 63) == 0) red[tid >> 6] = ss;
  __syncthreads();
  const float tot = red[0] + red[1] + red[2] + red[3];
  const float scale = rsqrtf(tot * (1.f / (float)D) + 1.1920929e-07f);
  const float4 wv = *reinterpret_cast<const float4*>(w + tid * 4);
  float4 o;
  o.x = v.x * scale * wv.x;
  o.y = v.y * scale * wv.y;
  o.z = v.z * scale * wv.z;
  o.w = v.w * scale * wv.w;
  *reinterpret_cast<float4*>(out + base + tid * 4) = o;
  if (WBF) {
    ushort4 ob; ob.x = f2b(o.x); ob.y = f2b(o.y); ob.z = f2b(o.z); ob.w = f2b(o.w);
    *reinterpret_cast<ushort4*>(xb + base + tid * 4) = ob;
  }
}

} // namespace

extern "C" void kernel_launch(void* const* d_in, const int* in_sizes, int n_in,
                              void* d_out, int out_size, void* d_ws, size_t ws_size,
                              hipStream_t stream)
{
  const float* x0     = (const float*)d_in[0];
  const float* in_w   = (const float*)d_in[1];
  const float* conv_w = (const float*)d_in[2];
  const float* conv_b = (const float*)d_in[3];
  const float* xp_w   = (const float*)d_in[4];
  const float* dtp_w  = (const float*)d_in[5];
  const float* dtp_b  = (const float*)d_in[6];
  const float* a_log  = (const float*)d_in[7];
  const float* d_par  = (const float*)d_in[8];
  const float* out_w  = (const float*)d_in[9];
  const float* w1     = (const float*)d_in[10];
  const float* b1     = (const float*)d_in[11];
  const float* w2     = (const float*)d_in[12];
  const float* b2     = (const float*)d_in[13];
  const float* ln_w   = (const float*)d_in[14];
  const float* ln2_w  = (const float*)d_in[15];
  float* out = (float*)d_out;

  // ---- workspace layout (212 MiB total) ----
  char* ws = (char*)d_ws;
  unsigned short* in_wb  = (unsigned short*)(ws);                 // 16 Mi: (NL,4096,1024) bf16
  unsigned short* out_wb = (unsigned short*)(ws + (16UL  << 20)); //  8 Mi: (NL,1024,2048)
  unsigned short* w1b    = (unsigned short*)(ws + (24UL  << 20)); //  4 Mi
  unsigned short* w2b    = (unsigned short*)(ws + (28UL  << 20)); //  4 Mi
  unsigned short* xbf    = (unsigned short*)(ws + (32UL  << 20)); // 16 Mi: layer input bf16
  unsigned short* zb     = (unsigned short*)(ws + (48UL  << 20)); // 32 Mi
  unsigned short* xc     = (unsigned short*)(ws + (80UL  << 20)); // 32 Mi
  float*          xdbl   = (float*)(ws + (112UL << 20));          //  3 Mi
  float*          sdtb   = (float*)(ws + (115UL << 20));          //  1 Mi
  float*          hendb  = (float*)(ws + (116UL << 20));          // 16 Mi
  unsigned short* xinb   = (unsigned short*)(ws + (132UL << 20)); // 32 Mi (alias: dt)
  unsigned short* dtb    = xinb;
  unsigned short* ybf    = (unsigned short*)(ws + (164UL << 20)); // 32 Mi (alias: hm)
  unsigned short* hm     = ybf;
  unsigned short* mo     = (unsigned short*)(ws + (196UL << 20)); // 16 Mi (alias: t2)
  unsigned short* t2     = mo;

  const dim3 blk(256);

  // one-time f32 -> bf16 conversions (weights + layer-0 input)
  cvt_bf16<<<dim3((2L*2*DI*D/4 + 255)/256), blk, 0, stream>>>(in_w,  in_wb,  2L*2*DI*D/4);
  cvt_bf16<<<dim3((2L*D*DI/4   + 255)/256), blk, 0, stream>>>(out_w, out_wb, 2L*D*DI/4);
  cvt_bf16<<<dim3((2L*D*D/4    + 255)/256), blk, 0, stream>>>(w1,    w1b,    2L*D*D/4);
  cvt_bf16<<<dim3((2L*D*D/4    + 255)/256), blk, 0, stream>>>(w2,    w2b,    2L*D*D/4);
  cvt_bf16<<<dim3(((long)ML*D/4+ 255)/256), blk, 0, stream>>>(x0,    xbf,    (long)ML*D/4);

  const float* xcur = x0;
  for (int layer = 0; layer < 2; ++layer) {
    const long lo = (long)layer;
    const unsigned short* Winb = in_wb + lo * 2 * DI * D;
    // 1a. x_in = x @ in_proj[0:2048]^T  (MFMA, N=2048, K=1024) -> xinb bf16
    gemm_mfma<0,false><<<dim3(DI/128, ML/128), blk, 0, stream>>>(
        xbf, D, Winb, D, nullptr, xinb, DI, D);
    // 1b. z = x @ in_proj[2048:4096]^T  (MFMA) -> zb bf16
    gemm_mfma<0,false><<<dim3(DI/128, ML/128), blk, 0, stream>>>(
        xbf, D, Winb + (long)DI * D, D, nullptr, zb, DI, D);
    // 2. xc = silu(causal_conv(x_in))
    conv_silu<<<dim3((long)ML*DI/4/256), blk, 0, stream>>>(
        xinb, conv_w + lo*DI*4, conv_b + lo*DI, xc);
    // 3. xdbl = xc @ x_proj^T  (f32 SGEMM, N=96, K=2048)
    gemm_bt<0,false,false,true><<<dim3(2, ML/128), blk, 0, stream>>>(
        xc, DI, xp_w + lo*96*DI, nullptr, xdbl, 96, 96, DI);
    // 4. dt = softplus(xdbl[:,:64] @ dt_proj^T + b)  (f32 SGEMM, N=2048, K=64) -> bf16
    gemm_bt<3,true,true,false><<<dim3(DI/64, ML/128), blk, 0, stream>>>(
        xdbl, 96, dtp_w + lo*DI*DTR, dtp_b + lo*DI, dtb, DI, DI, DTR);
    // 5. chunked selective scan -> ybf bf16
    scan_p1<<<dim3(Bsz*NCH*(DI/256)), blk, 0, stream>>>(
        dtb, xc, xdbl, a_log + lo*DI*DSTATE, hendb, sdtb);
    scan_p2<<<dim3(Bsz*DSTATE*DI/256), blk, 0, stream>>>(
        hendb, sdtb, a_log + lo*DI*DSTATE);
    scan_p3<<<dim3(Bsz*NCH*(DI/256)), blk, 0, stream>>>(
        dtb, xc, xdbl, zb, a_log + lo*DI*DSTATE, d_par + lo*DI, hendb, ybf);
    // 6. mo = y @ out_proj^T  (MFMA, N=1024, K=2048)
    gemm_mfma<0,false><<<dim3(D/128, ML/128), blk, 0, stream>>>(
        ybf, DI, out_wb + lo*D*DI, DI, nullptr, mo, D, DI);
    // 7. hm = gelu(mo @ w1^T + b1)  (MFMA, N=2048, K=1024)
    gemm_mfma<2,true><<<dim3(2*D/128, ML/128), blk, 0, stream>>>(
        mo, D, w1b, D, b1, hm, 2*D, D);
    // 8. t2 = gelu(hm @ w2^T + b2)  (MFMA, N=1024, K=2048)
    gemm_mfma<2,true><<<dim3(D/128, ML/128), blk, 0, stream>>>(
        hm, 2*D, w2b, 2*D, b2, t2, D, 2*D);
    // 9. x = rmsnorm(t2 + residual) -> out (f32) + xbf (bf16)
    add_rmsnorm<true,true><<<dim3(ML), blk, 0, stream>>>(t2, xcur, ln_w, out, xbf);
    xcur = out;
  }
  // final: rmsnorm(x + residual2)
  add_rmsnorm<false,false><<<dim3(ML), blk, 0, stream>>>(out, x0, ln2_w, out, nullptr);
}

// Round 5
// 1291.486 us; speedup vs baseline: 6.6099x; 1.2853x over previous
//
#include <hip/hip_runtime.h>
#include <math.h>

namespace {

constexpr int Bsz = 4;
constexpr int L   = 2048;
constexpr int D   = 1024;
constexpr int DI  = 2048;
constexpr int DSTATE = 16;
constexpr int DTR = 64;
constexpr int ML  = Bsz * L; // 8192 rows
constexpr int NCH = 32;      // chunks per sequence
constexpr int CL  = 64;      // chunk length

typedef __attribute__((ext_vector_type(8))) short bfrag;   // 8 bf16 (4 VGPRs)
typedef __attribute__((ext_vector_type(4))) float f32x4;

// ---- bf16 bit helpers (RNE) ----
__device__ __forceinline__ unsigned short f2b(float f) {
  union { float f; unsigned int u; } c; c.f = f;
  unsigned int u = c.u;
  unsigned int r = (u + 0x7fffu + ((u >> 16) & 1u)) >> 16;
  return (unsigned short)r;
}
__device__ __forceinline__ float b2f(unsigned short h) {
  union { unsigned int u; float f; } c; c.u = ((unsigned int)h) << 16;
  return c.f;
}

// ---- async global->LDS 16B ----
__device__ __forceinline__ void async16(const void* g, void* l) {
  __builtin_amdgcn_global_load_lds(
      (const __attribute__((address_space(1))) void*)g,
      (__attribute__((address_space(3))) void*)l, 16, 0, 0);
}

// ---------------- activations ----------------
template<int ACT>
__device__ __forceinline__ float activate(float x) {
  if (ACT == 1) { return x / (1.f + expf(-x)); }
  if (ACT == 2) { return 0.5f * x * (1.f + erff(x * 0.7071067811865475f)); }
  if (ACT == 3) { return (x > 20.f) ? x : log1pf(expf(x)); }
  return x;
}

// ---------------- bf16 MFMA GEMM: C(bf16) = act(A * W^T + bias) ----------------
// A: (M x K) bf16 row-major stride lda; W: (N x K) bf16 row-major stride ldw.
// 128x128 tile, BK=32, 4 waves (2x2), mfma_f32_16x16x32_bf16.
template<int ACT, bool HAS_BIAS>
__global__ __launch_bounds__(256) void gemm_mfma(
    const unsigned short* __restrict__ A, long lda,
    const unsigned short* __restrict__ W, long ldw,
    const float* __restrict__ bias,
    unsigned short* __restrict__ C, long ldc,
    int K)
{
  __shared__ unsigned short As[128 * 32];
  __shared__ unsigned short Bs[128 * 32];
  const int tid  = threadIdx.x;
  const int lane = tid & 63;
  const int w    = tid >> 6;
  const int wr   = w >> 1, wc = w & 1;
  const long bm = (long)blockIdx.y * 128;
  const long bn = (long)blockIdx.x * 128;

  const int srow = tid >> 2;
  const int scol = (tid & 3) * 8;
  const unsigned short* ga0 = A + (bm + srow)      * lda + scol;
  const unsigned short* ga1 = A + (bm + 64 + srow) * lda + scol;
  const unsigned short* gb0 = W + (bn + srow)      * ldw + scol;
  const unsigned short* gb1 = W + (bn + 64 + srow) * ldw + scol;
  char* lA = (char*)As;
  char* lB = (char*)Bs;
  const int loff = tid * 16;

  const int frow = lane & 15;
  const int fko  = (lane >> 4) * 8;

  f32x4 acc[4][4];
  #pragma unroll
  for (int m = 0; m < 4; ++m)
    #pragma unroll
    for (int n = 0; n < 4; ++n)
      acc[m][n] = (f32x4){0.f, 0.f, 0.f, 0.f};

  for (int k0 = 0; k0 < K; k0 += 32) {
    __syncthreads();
    async16(ga0 + k0, lA + loff);
    async16(ga1 + k0, lA + 4096 + loff);
    async16(gb0 + k0, lB + loff);
    async16(gb1 + k0, lB + 4096 + loff);
    __syncthreads();
    bfrag a[4], b[4];
    #pragma unroll
    for (int m = 0; m < 4; ++m)
      a[m] = *reinterpret_cast<const bfrag*>(&As[(wr*64 + m*16 + frow)*32 + fko]);
    #pragma unroll
    for (int n = 0; n < 4; ++n)
      b[n] = *reinterpret_cast<const bfrag*>(&Bs[(wc*64 + n*16 + frow)*32 + fko]);
    #pragma unroll
    for (int m = 0; m < 4; ++m)
      #pragma unroll
      for (int n = 0; n < 4; ++n)
        acc[m][n] = __builtin_amdgcn_mfma_f32_16x16x32_bf16(a[m], b[n], acc[m][n], 0, 0, 0);
  }

  #pragma unroll
  for (int n = 0; n < 4; ++n) {
    const long col = bn + wc*64 + n*16 + frow;
    const float bv = HAS_BIAS ? bias[col] : 0.f;
    #pragma unroll
    for (int m = 0; m < 4; ++m) {
      const long row = bm + wr*64 + m*16 + (lane >> 4) * 4;
      #pragma unroll
      for (int j = 0; j < 4; ++j) {
        float v = acc[m][n][j] + bv;
        v = activate<ACT>(v);
        C[(row + j) * ldc + col] = f2b(v);
      }
    }
  }
}

// ---------------- x_proj MFMA: xdbl(f32, ML x 96) = xc @ xp_w^T ----------------
// BM=64, BN=96, BK=32; 4 waves, each wave 16 rows x 96 cols.
// Also emits bf16 copy of cols [0,64) into dtr for the dt_proj GEMM.
__global__ __launch_bounds__(256) void xproj_mfma(
    const unsigned short* __restrict__ A,   // xc (ML x DI)
    const unsigned short* __restrict__ W,   // xp_wb (96 x DI)
    float* __restrict__ xdbl,               // (ML x 96) f32
    unsigned short* __restrict__ dtr)       // (ML x 64) bf16
{
  __shared__ unsigned short As[64 * 32];
  __shared__ unsigned short Bs[96 * 32];
  const int tid  = threadIdx.x;
  const int lane = tid & 63;
  const int wv   = tid >> 6;
  const long bm  = (long)blockIdx.x * 64;

  const int arow = tid >> 2;          // 0..63
  const int acol = (tid & 3) * 8;
  const unsigned short* ga  = A + (bm + arow) * DI + acol;
  const unsigned short* gb0 = W + (long)(tid >> 2) * DI + acol;          // rows 0..63
  const unsigned short* gb1 = W + (long)((tid >> 2) + 64) * DI + acol;   // rows 64..95
  char* lA = (char*)As;
  char* lB = (char*)Bs;

  const int frow = lane & 15;
  const int fko  = (lane >> 4) * 8;

  f32x4 acc[6];
  #pragma unroll
  for (int n = 0; n < 6; ++n) acc[n] = (f32x4){0.f, 0.f, 0.f, 0.f};

  for (int k0 = 0; k0 < DI; k0 += 32) {
    __syncthreads();
    async16(ga + k0, lA + tid * 16);
    async16(gb0 + k0, lB + tid * 16);
    if (tid < 128) async16(gb1 + k0, lB + 4096 + tid * 16);
    __syncthreads();
    const bfrag a = *reinterpret_cast<const bfrag*>(&As[(wv*16 + frow)*32 + fko]);
    #pragma unroll
    for (int n = 0; n < 6; ++n) {
      const bfrag b = *reinterpret_cast<const bfrag*>(&Bs[(n*16 + frow)*32 + fko]);
      acc[n] = __builtin_amdgcn_mfma_f32_16x16x32_bf16(a, b, acc[n], 0, 0, 0);
    }
  }

  const int r0 = wv*16 + (lane >> 4) * 4;
  #pragma unroll
  for (int n = 0; n < 6; ++n) {
    const int col = n*16 + frow;
    #pragma unroll
    for (int j = 0; j < 4; ++j) {
      const long row = bm + r0 + j;
      const float v = acc[n][j];
      xdbl[row * 96 + col] = v;
      if (n < 4) dtr[row * 64 + col] = f2b(v);
    }
  }
}

// ---------------- f32 -> bf16 convert ----------------
__global__ __launch_bounds__(256) void cvt_bf16(
    const float* __restrict__ in, unsigned short* __restrict__ out, long n4)
{
  const long i = (long)blockIdx.x * 256 + threadIdx.x;
  if (i < n4) {
    const float4 v = reinterpret_cast<const float4*>(in)[i];
    ushort4 o; o.x = f2b(v.x); o.y = f2b(v.y); o.z = f2b(v.z); o.w = f2b(v.w);
    reinterpret_cast<ushort4*>(out)[i] = o;
  }
}

// ---------------- depthwise causal conv (k=4) + silu, bf16 in/out ----------------
__global__ __launch_bounds__(256) void conv_silu(
    const unsigned short* __restrict__ xin,
    const float* __restrict__ w,     // (DI, 4) f32
    const float* __restrict__ bias,  // (DI) f32
    unsigned short* __restrict__ xc)
{
  const int idx = blockIdx.x * 256 + threadIdx.x;
  const int D4 = DI / 4;
  const int d  = (idx % D4) * 4;
  const int bt = idx / D4;
  const int t  = bt & (L - 1);
  const int b  = bt >> 11;
  const float4 w0 = *reinterpret_cast<const float4*>(w + (long)(d+0)*4);
  const float4 w1 = *reinterpret_cast<const float4*>(w + (long)(d+1)*4);
  const float4 w2 = *reinterpret_cast<const float4*>(w + (long)(d+2)*4);
  const float4 w3 = *reinterpret_cast<const float4*>(w + (long)(d+3)*4);
  const float4 bv = *reinterpret_cast<const float4*>(bias + d);
  float a0 = bv.x, a1 = bv.y, a2 = bv.z, a3 = bv.w;
  const float wk0[4] = {w0.x, w0.y, w0.z, w0.w};
  const float wk1[4] = {w1.x, w1.y, w1.z, w1.w};
  const float wk2[4] = {w2.x, w2.y, w2.z, w2.w};
  const float wk3[4] = {w3.x, w3.y, w3.z, w3.w};
  #pragma unroll
  for (int k = 0; k < 4; ++k) {
    const int tt = t - 3 + k;
    if (tt >= 0) {
      const ushort4 xv = *reinterpret_cast<const ushort4*>(xin + ((long)(b * L + tt)) * DI + d);
      a0 = fmaf(wk0[k], b2f(xv.x), a0);
      a1 = fmaf(wk1[k], b2f(xv.y), a1);
      a2 = fmaf(wk2[k], b2f(xv.z), a2);
      a3 = fmaf(wk3[k], b2f(xv.w), a3);
    }
  }
  a0 = a0 / (1.f + expf(-a0));
  a1 = a1 / (1.f + expf(-a1));
  a2 = a2 / (1.f + expf(-a2));
  a3 = a3 / (1.f + expf(-a3));
  ushort4 o; o.x = f2b(a0); o.y = f2b(a1); o.z = f2b(a2); o.w = f2b(a3);
  *reinterpret_cast<ushort4*>(xc + (long)bt * DI + d) = o;
}

// ---------------- chunked selective scan ----------------
__global__ __launch_bounds__(256) void scan_p1(
    const unsigned short* __restrict__ dt,   // (ML, DI) bf16
    const unsigned short* __restrict__ u,    // (ML, DI) bf16
    const float* __restrict__ xdbl,          // (ML, 96): B at 64
    const float* __restrict__ a_log,         // (DI, 16)
    float* __restrict__ hend,                // (Bsz, NCH, 16, DI)
    float* __restrict__ sdt)                 // (Bsz, NCH, DI)
{
  const int bid = blockIdx.x;
  const int dg = bid & 7;
  const int c  = (bid >> 3) & (NCH - 1);
  const int b  = bid >> 8;
  const int d  = dg * 256 + threadIdx.x;
  float A[16];
  #pragma unroll
  for (int q = 0; q < 4; ++q) {
    const float4 al = *reinterpret_cast<const float4*>(a_log + (long)d * 16 + q * 4);
    A[q*4+0] = -__expf(al.x); A[q*4+1] = -__expf(al.y);
    A[q*4+2] = -__expf(al.z); A[q*4+3] = -__expf(al.w);
  }
  float h[16];
  #pragma unroll
  for (int s = 0; s < 16; ++s) h[s] = 0.f;
  float s_dt = 0.f;
  const long row0 = (long)b * L + (long)c * CL;
  for (int t = 0; t < CL; ++t) {
    const long row = row0 + t;
    const float dtv = b2f(dt[row * DI + d]);
    const float uv  = b2f(u [row * DI + d]);
    const float* bp = xdbl + row * 96 + 64;
    const float4 B0 = *reinterpret_cast<const float4*>(bp + 0);
    const float4 B1 = *reinterpret_cast<const float4*>(bp + 4);
    const float4 B2 = *reinterpret_cast<const float4*>(bp + 8);
    const float4 B3 = *reinterpret_cast<const float4*>(bp + 12);
    const float Bv[16] = {B0.x,B0.y,B0.z,B0.w, B1.x,B1.y,B1.z,B1.w,
                          B2.x,B2.y,B2.z,B2.w, B3.x,B3.y,B3.z,B3.w};
    s_dt += dtv;
    const float dtu = dtv * uv;
    #pragma unroll
    for (int s = 0; s < 16; ++s)
      h[s] = fmaf(__expf(dtv * A[s]), h[s], dtu * Bv[s]);
  }
  const long cb = (long)(b * NCH + c);
  #pragma unroll
  for (int s = 0; s < 16; ++s)
    hend[(cb * 16 + s) * DI + d] = h[s];
  sdt[cb * DI + d] = s_dt;
}

__global__ __launch_bounds__(256) void scan_p2(
    float* __restrict__ hend,
    const float* __restrict__ sdt,
    const float* __restrict__ a_log)
{
  const long idx = (long)blockIdx.x * 256 + threadIdx.x;
  const int d = idx & (DI - 1);
  const int s = (idx >> 11) & 15;
  const int b = idx >> 15;
  const float A = -__expf(a_log[(long)d * 16 + s]);
  float h = 0.f;
  for (int c = 0; c < NCH; ++c) {
    const long cb = (long)(b * NCH + c);
    const long off = (cb * 16 + s) * DI + d;
    const float hl = hend[off];
    const float sd = sdt[cb * DI + d];
    hend[off] = h;
    h = fmaf(__expf(A * sd), h, hl);
  }
}

__global__ __launch_bounds__(256) void scan_p3(
    const unsigned short* __restrict__ dt,
    const unsigned short* __restrict__ u,
    const float* __restrict__ xdbl,          // B at 64, C at 80
    const unsigned short* __restrict__ z,
    const float* __restrict__ a_log,
    const float* __restrict__ dpar,
    const float* __restrict__ hinit,
    unsigned short* __restrict__ y)
{
  const int bid = blockIdx.x;
  const int dg = bid & 7;
  const int c  = (bid >> 3) & (NCH - 1);
  const int b  = bid >> 8;
  const int d  = dg * 256 + threadIdx.x;
  float A[16];
  #pragma unroll
  for (int q = 0; q < 4; ++q) {
    const float4 al = *reinterpret_cast<const float4*>(a_log + (long)d * 16 + q * 4);
    A[q*4+0] = -__expf(al.x); A[q*4+1] = -__expf(al.y);
    A[q*4+2] = -__expf(al.z); A[q*4+3] = -__expf(al.w);
  }
  const float Dv = dpar[d];
  const long cb = (long)(b * NCH + c);
  float h[16];
  #pragma unroll
  for (int s = 0; s < 16; ++s)
    h[s] = hinit[(cb * 16 + s) * DI + d];
  const long row0 = (long)b * L + (long)c * CL;
  for (int t = 0; t < CL; ++t) {
    const long row = row0 + t;
    const float dtv = b2f(dt[row * DI + d]);
    const float uv  = b2f(u [row * DI + d]);
    const float* bp = xdbl + row * 96 + 64;
    const float4 B0 = *reinterpret_cast<const float4*>(bp + 0);
    const float4 B1 = *reinterpret_cast<const float4*>(bp + 4);
    const float4 B2 = *reinterpret_cast<const float4*>(bp + 8);
    const float4 B3 = *reinterpret_cast<const float4*>(bp + 12);
    const float4 C0 = *reinterpret_cast<const float4*>(bp + 16);
    const float4 C1 = *reinterpret_cast<const float4*>(bp + 20);
    const float4 C2 = *reinterpret_cast<const float4*>(bp + 24);
    const float4 C3 = *reinterpret_cast<const float4*>(bp + 28);
    const float Bv[16] = {B0.x,B0.y,B0.z,B0.w, B1.x,B1.y,B1.z,B1.w,
                          B2.x,B2.y,B2.z,B2.w, B3.x,B3.y,B3.z,B3.w};
    const float Cv[16] = {C0.x,C0.y,C0.z,C0.w, C1.x,C1.y,C1.z,C1.w,
                          C2.x,C2.y,C2.z,C2.w, C3.x,C3.y,C3.z,C3.w};
    const float dtu = dtv * uv;
    float yv = 0.f;
    #pragma unroll
    for (int s = 0; s < 16; ++s) {
      h[s] = fmaf(__expf(dtv * A[s]), h[s], dtu * Bv[s]);
      yv = fmaf(h[s], Cv[s], yv);
    }
    const float zv = b2f(z[row * DI + d]);
    const float sg = zv / (1.f + __expf(-zv));
    y[row * DI + d] = f2b(fmaf(uv, Dv, yv) * sg);
  }
}

// ---------------- fused add-residual + rmsnorm ----------------
template<bool BIN, bool WBF>
__global__ __launch_bounds__(256) void add_rmsnorm(
    const void* __restrict__ xinp, const float* __restrict__ res,
    const float* __restrict__ w, float* __restrict__ out,
    unsigned short* __restrict__ xb)
{
  const int row = blockIdx.x;
  const int tid = threadIdx.x;
  const long base = (long)row * D;
  float4 v;
  if (BIN) {
    const ushort4 t = *reinterpret_cast<const ushort4*>((const unsigned short*)xinp + base + tid * 4);
    v.x = b2f(t.x); v.y = b2f(t.y); v.z = b2f(t.z); v.w = b2f(t.w);
  } else {
    v = *reinterpret_cast<const float4*>((const float*)xinp + base + tid * 4);
  }
  const float4 r = *reinterpret_cast<const float4*>(res + base + tid * 4);
  v.x += r.x; v.y += r.y; v.z += r.z; v.w += r.w;
  float ss = v.x*v.x + v.y*v.y + v.z*v.z + v.w*v.w;
  #pragma unroll
  for (int m = 1; m < 64; m <<= 1) ss += __shfl_xor(ss, m);
  __shared__ float red[4];
  if ((tid & 63) == 0) red[tid >> 6] = ss;
  __syncthreads();
  const float tot = red[0] + red[1] + red[2] + red[3];
  const float scale = rsqrtf(tot * (1.f / (float)D) + 1.1920929e-07f);
  const float4 wv = *reinterpret_cast<const float4*>(w + tid * 4);
  float4 o;
  o.x = v.x * scale * wv.x;
  o.y = v.y * scale * wv.y;
  o.z = v.z * scale * wv.z;
  o.w = v.w * scale * wv.w;
  *reinterpret_cast<float4*>(out + base + tid * 4) = o;
  if (WBF) {
    ushort4 ob; ob.x = f2b(o.x); ob.y = f2b(o.y); ob.z = f2b(o.z); ob.w = f2b(o.w);
    *reinterpret_cast<ushort4*>(xb + base + tid * 4) = ob;
  }
}

} // namespace

extern "C" void kernel_launch(void* const* d_in, const int* in_sizes, int n_in,
                              void* d_out, int out_size, void* d_ws, size_t ws_size,
                              hipStream_t stream)
{
  const float* x0     = (const float*)d_in[0];
  const float* in_w   = (const float*)d_in[1];
  const float* conv_w = (const float*)d_in[2];
  const float* conv_b = (const float*)d_in[3];
  const float* xp_w   = (const float*)d_in[4];
  const float* dtp_w  = (const float*)d_in[5];
  const float* dtp_b  = (const float*)d_in[6];
  const float* a_log  = (const float*)d_in[7];
  const float* d_par  = (const float*)d_in[8];
  const float* out_w  = (const float*)d_in[9];
  const float* w1     = (const float*)d_in[10];
  const float* b1     = (const float*)d_in[11];
  const float* w2     = (const float*)d_in[12];
  const float* b2     = (const float*)d_in[13];
  const float* ln_w   = (const float*)d_in[14];
  const float* ln2_w  = (const float*)d_in[15];
  float* out = (float*)d_out;

  // ---- workspace layout (~216 MiB total) ----
  char* ws = (char*)d_ws;
  unsigned short* in_wb  = (unsigned short*)(ws);                 // 16 Mi
  unsigned short* out_wb = (unsigned short*)(ws + (16UL  << 20)); //  8 Mi
  unsigned short* w1b    = (unsigned short*)(ws + (24UL  << 20)); //  4 Mi
  unsigned short* w2b    = (unsigned short*)(ws + (28UL  << 20)); //  4 Mi
  unsigned short* xbf    = (unsigned short*)(ws + (32UL  << 20)); // 16 Mi
  unsigned short* zb     = (unsigned short*)(ws + (48UL  << 20)); // 32 Mi
  unsigned short* xc     = (unsigned short*)(ws + (80UL  << 20)); // 32 Mi
  float*          xdbl   = (float*)(ws + (112UL << 20));          //  3 Mi
  float*          sdtb   = (float*)(ws + (115UL << 20));          //  1 Mi
  float*          hendb  = (float*)(ws + (116UL << 20));          // 16 Mi
  unsigned short* xinb   = (unsigned short*)(ws + (132UL << 20)); // 32 Mi (alias: dt)
  unsigned short* dtb    = xinb;
  unsigned short* ybf    = (unsigned short*)(ws + (164UL << 20)); // 32 Mi (alias: hm)
  unsigned short* hm     = ybf;
  unsigned short* mo     = (unsigned short*)(ws + (196UL << 20)); // 16 Mi (alias: t2)
  unsigned short* t2     = mo;
  unsigned short* xp_wb  = (unsigned short*)(ws + (212UL << 20)); // 0.75 Mi
  unsigned short* dtp_wb = (unsigned short*)(ws + (213UL << 20)); // 0.5 Mi
  unsigned short* dtrb   = (unsigned short*)(ws + (214UL << 20)); // 1 Mi: (ML,64) bf16

  const dim3 blk(256);

  // one-time f32 -> bf16 conversions (weights + layer-0 input)
  cvt_bf16<<<dim3((2L*2*DI*D/4 + 255)/256), blk, 0, stream>>>(in_w,  in_wb,  2L*2*DI*D/4);
  cvt_bf16<<<dim3((2L*D*DI/4   + 255)/256), blk, 0, stream>>>(out_w, out_wb, 2L*D*DI/4);
  cvt_bf16<<<dim3((2L*D*D/4    + 255)/256), blk, 0, stream>>>(w1,    w1b,    2L*D*D/4);
  cvt_bf16<<<dim3((2L*D*D/4    + 255)/256), blk, 0, stream>>>(w2,    w2b,    2L*D*D/4);
  cvt_bf16<<<dim3((2L*96*DI/4  + 255)/256), blk, 0, stream>>>(xp_w,  xp_wb,  2L*96*DI/4);
  cvt_bf16<<<dim3((2L*DI*DTR/4 + 255)/256), blk, 0, stream>>>(dtp_w, dtp_wb, 2L*DI*DTR/4);
  cvt_bf16<<<dim3(((long)ML*D/4+ 255)/256), blk, 0, stream>>>(x0,    xbf,    (long)ML*D/4);

  const float* xcur = x0;
  for (int layer = 0; layer < 2; ++layer) {
    const long lo = (long)layer;
    const unsigned short* Winb = in_wb + lo * 2 * DI * D;
    // 1a. x_in = x @ in_proj[0:2048]^T  (MFMA, N=2048, K=1024)
    gemm_mfma<0,false><<<dim3(DI/128, ML/128), blk, 0, stream>>>(
        xbf, D, Winb, D, nullptr, xinb, DI, D);
    // 1b. z = x @ in_proj[2048:4096]^T  (MFMA)
    gemm_mfma<0,false><<<dim3(DI/128, ML/128), blk, 0, stream>>>(
        xbf, D, Winb + (long)DI * D, D, nullptr, zb, DI, D);
    // 2. xc = silu(causal_conv(x_in))
    conv_silu<<<dim3((long)ML*DI/4/256), blk, 0, stream>>>(
        xinb, conv_w + lo*DI*4, conv_b + lo*DI, xc);
    // 3. xdbl = xc @ x_proj^T  (MFMA, N=96, K=2048) + bf16 dt cols
    xproj_mfma<<<dim3(ML/64), blk, 0, stream>>>(
        xc, xp_wb + lo*96*DI, xdbl, dtrb);
    // 4. dt = softplus(dtr @ dt_proj^T + b)  (MFMA, N=2048, K=64)
    gemm_mfma<3,true><<<dim3(DI/128, ML/128), blk, 0, stream>>>(
        dtrb, DTR, dtp_wb + lo*DI*DTR, DTR, dtp_b + lo*DI, dtb, DI, DTR);
    // 5. chunked selective scan -> ybf bf16
    scan_p1<<<dim3(Bsz*NCH*(DI/256)), blk, 0, stream>>>(
        dtb, xc, xdbl, a_log + lo*DI*DSTATE, hendb, sdtb);
    scan_p2<<<dim3(Bsz*DSTATE*DI/256), blk, 0, stream>>>(
        hendb, sdtb, a_log + lo*DI*DSTATE);
    scan_p3<<<dim3(Bsz*NCH*(DI/256)), blk, 0, stream>>>(
        dtb, xc, xdbl, zb, a_log + lo*DI*DSTATE, d_par + lo*DI, hendb, ybf);
    // 6. mo = y @ out_proj^T  (MFMA, N=1024, K=2048)
    gemm_mfma<0,false><<<dim3(D/128, ML/128), blk, 0, stream>>>(
        ybf, DI, out_wb + lo*D*DI, DI, nullptr, mo, D, DI);
    // 7. hm = gelu(mo @ w1^T + b1)  (MFMA, N=2048, K=1024)
    gemm_mfma<2,true><<<dim3(2*D/128, ML/128), blk, 0, stream>>>(
        mo, D, w1b, D, b1, hm, 2*D, D);
    // 8. t2 = gelu(hm @ w2^T + b2)  (MFMA, N=1024, K=2048)
    gemm_mfma<2,true><<<dim3(D/128, ML/128), blk, 0, stream>>>(
        hm, 2*D, w2b, 2*D, b2, t2, D, 2*D);
    // 9. x = rmsnorm(t2 + residual) -> out (f32) + xbf (bf16)
    add_rmsnorm<true,true><<<dim3(ML), blk, 0, stream>>>(t2, xcur, ln_w, out, xbf);
    xcur = out;
  }
  // final: rmsnorm(x + residual2)
  add_rmsnorm<false,false><<<dim3(ML), blk, 0, stream>>>(out, x0, ln2_w, out, nullptr);
}

// Round 6
// 1150.153 us; speedup vs baseline: 7.4221x; 1.1229x over previous
//
#include <hip/hip_runtime.h>
#include <math.h>

namespace {

constexpr int Bsz = 4;
constexpr int L   = 2048;
constexpr int D   = 1024;
constexpr int DI  = 2048;
constexpr int DSTATE = 16;
constexpr int DTR = 64;
constexpr int ML  = Bsz * L; // 8192 rows
constexpr int NCH = 32;      // chunks per sequence
constexpr int CL  = 64;      // chunk length

typedef __attribute__((ext_vector_type(8))) short bfrag;   // 8 bf16 (4 VGPRs)
typedef __attribute__((ext_vector_type(4))) float f32x4;

// ---- bf16 bit helpers (RNE) ----
__device__ __forceinline__ unsigned short f2b(float f) {
  union { float f; unsigned int u; } c; c.f = f;
  unsigned int u = c.u;
  unsigned int r = (u + 0x7fffu + ((u >> 16) & 1u)) >> 16;
  return (unsigned short)r;
}
__device__ __forceinline__ float b2f(unsigned short h) {
  union { unsigned int u; float f; } c; c.u = ((unsigned int)h) << 16;
  return c.f;
}

// ---- async global->LDS 16B ----
__device__ __forceinline__ void async16(const void* g, void* l) {
  __builtin_amdgcn_global_load_lds(
      (const __attribute__((address_space(1))) void*)g,
      (__attribute__((address_space(3))) void*)l, 16, 0, 0);
}

// ---------------- activations ----------------
template<int ACT>
__device__ __forceinline__ float activate(float x) {
  if (ACT == 1) { return x / (1.f + expf(-x)); }
  if (ACT == 2) { return 0.5f * x * (1.f + erff(x * 0.7071067811865475f)); }
  if (ACT == 3) { return (x > 20.f) ? x : log1pf(expf(x)); }
  return x;
}

// ---------------- 256-tile 2-phase bf16 MFMA GEMM ----------------
// C = act(A @ W^T + bias).  A: (M x K) bf16 stride lda; W: (N x K) bf16 stride ldw.
// BM=256, BN template (256 or 128), BK=64, 512 threads = 8 waves (2M x 4N).
// LDS double-buffered, global_load_lds staging with both-sides chunk^(row&7)
// swizzle (linear LDS dest + permuted global source + permuted read: rule 21).
// SPLIT: cols [0,2048) -> C0, [2048,4096) -> C1 (both ldc).
template<int ACT, bool HAS_BIAS, int BN, bool SPLIT>
__global__ __launch_bounds__(512) void gemm2(
    const unsigned short* __restrict__ A, long lda,
    const unsigned short* __restrict__ W, long ldw,
    const float* __restrict__ bias,
    unsigned short* __restrict__ C0,
    unsigned short* __restrict__ C1,
    long ldc, int K)
{
  constexpr int NB   = BN / 64;      // n-frags per wave (4 or 2)
  constexpr int ABUF = 256 * 64;     // elems per A buffer
  constexpr int BBUF = BN * 64;
  __shared__ unsigned short lds[2 * ABUF + 2 * BBUF];

  const int tid  = threadIdx.x;
  const int lane = tid & 63;
  const int wid  = tid >> 6;
  const int wr   = wid >> 2;         // 0..1
  const int wc   = wid & 3;          // 0..3
  const int frow = lane & 15;
  const int klg  = lane >> 4;

  // bijective XCD swizzle (nwg % 8 == 0 for all our grids)
  const int gx = gridDim.x;
  int id = blockIdx.y * gx + blockIdx.x;
  const int q = (gx * gridDim.y) >> 3;
  id = (id & 7) * q + (id >> 3);
  const int bx = id % gx;
  const int by = id / gx;
  const long bm = (long)by * 256;
  const long bn = (long)bx * BN;

  unsigned short* Cb;
  long cbase;
  if (SPLIT) {
    if (bn < 2048) { Cb = C0; cbase = bn; }
    else           { Cb = C1; cbase = bn - 2048; }
  } else { Cb = C0; cbase = bn; }

  f32x4 acc[8][NB];
  #pragma unroll
  for (int m = 0; m < 8; ++m)
    #pragma unroll
    for (int n = 0; n < NB; ++n)
      acc[m][n] = (f32x4){0.f, 0.f, 0.f, 0.f};

  auto stage = [&](int kt, int p) {
    const long kcol = (long)kt * 64;
    #pragma unroll
    for (int l = 0; l < 4; ++l) {                  // A: 4 loads/thread
      const int idx = tid + l * 512;               // [0, 2048)
      const int row = idx >> 3;                    // [0, 256)
      const int ch  = (idx & 7) ^ (row & 7);
      async16(A + (bm + row) * lda + kcol + ch * 8,
              &lds[p * ABUF + idx * 8]);
    }
    #pragma unroll
    for (int l = 0; l < NB; ++l) {                 // B: BN/64 loads/thread
      const int idx = tid + l * 512;               // [0, BN*8)
      const int row = idx >> 3;                    // [0, BN)
      const int ch  = (idx & 7) ^ (row & 7);
      async16(W + (bn + row) * ldw + kcol + ch * 8,
              &lds[2 * ABUF + p * BBUF + idx * 8]);
    }
  };

  stage(0, 0);
  __syncthreads();
  const int NT = K >> 6;
  for (int kt = 0; kt < NT; ++kt) {
    if (kt + 1 < NT) stage(kt + 1, (kt + 1) & 1);
    const unsigned short* Ab = &lds[(kt & 1) * ABUF];
    const unsigned short* Bb = &lds[2 * ABUF + (kt & 1) * BBUF];
    #pragma unroll
    for (int kk = 0; kk < 2; ++kk) {
      bfrag av[8], bv[NB];
      #pragma unroll
      for (int m = 0; m < 8; ++m) {
        const int r  = wr * 128 + m * 16 + frow;
        const int ch = (kk * 4 + klg) ^ (r & 7);
        av[m] = *reinterpret_cast<const bfrag*>(&Ab[r * 64 + ch * 8]);
      }
      #pragma unroll
      for (int n = 0; n < NB; ++n) {
        const int r  = wc * (BN / 4) + n * 16 + frow;
        const int ch = (kk * 4 + klg) ^ (r & 7);
        bv[n] = *reinterpret_cast<const bfrag*>(&Bb[r * 64 + ch * 8]);
      }
      #pragma unroll
      for (int m = 0; m < 8; ++m)
        #pragma unroll
        for (int n = 0; n < NB; ++n)
          acc[m][n] = __builtin_amdgcn_mfma_f32_16x16x32_bf16(av[m], bv[n], acc[m][n], 0, 0, 0);
    }
    __syncthreads();
  }

  // epilogue: D col = lane&15, row = (lane>>4)*4 + j
  #pragma unroll
  for (int n = 0; n < NB; ++n) {
    const int noff = wc * (BN / 4) + n * 16 + frow;
    const float bv = HAS_BIAS ? bias[bn + noff] : 0.f;
    #pragma unroll
    for (int m = 0; m < 8; ++m) {
      const long row = bm + wr * 128 + m * 16 + klg * 4;
      #pragma unroll
      for (int j = 0; j < 4; ++j) {
        float v = acc[m][n][j] + bv;
        v = activate<ACT>(v);
        Cb[(row + j) * ldc + cbase + noff] = f2b(v);
      }
    }
  }
}

// ---------------- 128-tile m97-style MFMA GEMM (dt_proj: K=64) ----------------
template<int ACT, bool HAS_BIAS>
__global__ __launch_bounds__(256) void gemm_mfma(
    const unsigned short* __restrict__ A, long lda,
    const unsigned short* __restrict__ W, long ldw,
    const float* __restrict__ bias,
    unsigned short* __restrict__ C, long ldc,
    int K)
{
  __shared__ unsigned short As[128 * 32];
  __shared__ unsigned short Bs[128 * 32];
  const int tid  = threadIdx.x;
  const int lane = tid & 63;
  const int w    = tid >> 6;
  const int wr   = w >> 1, wc = w & 1;
  const long bm = (long)blockIdx.y * 128;
  const long bn = (long)blockIdx.x * 128;

  const int srow = tid >> 2;
  const int scol = (tid & 3) * 8;
  const unsigned short* ga0 = A + (bm + srow)      * lda + scol;
  const unsigned short* ga1 = A + (bm + 64 + srow) * lda + scol;
  const unsigned short* gb0 = W + (bn + srow)      * ldw + scol;
  const unsigned short* gb1 = W + (bn + 64 + srow) * ldw + scol;
  char* lA = (char*)As;
  char* lB = (char*)Bs;
  const int loff = tid * 16;

  const int frow = lane & 15;
  const int fko  = (lane >> 4) * 8;

  f32x4 acc[4][4];
  #pragma unroll
  for (int m = 0; m < 4; ++m)
    #pragma unroll
    for (int n = 0; n < 4; ++n)
      acc[m][n] = (f32x4){0.f, 0.f, 0.f, 0.f};

  for (int k0 = 0; k0 < K; k0 += 32) {
    __syncthreads();
    async16(ga0 + k0, lA + loff);
    async16(ga1 + k0, lA + 4096 + loff);
    async16(gb0 + k0, lB + loff);
    async16(gb1 + k0, lB + 4096 + loff);
    __syncthreads();
    bfrag a[4], b[4];
    #pragma unroll
    for (int m = 0; m < 4; ++m)
      a[m] = *reinterpret_cast<const bfrag*>(&As[(wr*64 + m*16 + frow)*32 + fko]);
    #pragma unroll
    for (int n = 0; n < 4; ++n)
      b[n] = *reinterpret_cast<const bfrag*>(&Bs[(wc*64 + n*16 + frow)*32 + fko]);
    #pragma unroll
    for (int m = 0; m < 4; ++m)
      #pragma unroll
      for (int n = 0; n < 4; ++n)
        acc[m][n] = __builtin_amdgcn_mfma_f32_16x16x32_bf16(a[m], b[n], acc[m][n], 0, 0, 0);
  }

  #pragma unroll
  for (int n = 0; n < 4; ++n) {
    const long col = bn + wc*64 + n*16 + frow;
    const float bv = HAS_BIAS ? bias[col] : 0.f;
    #pragma unroll
    for (int m = 0; m < 4; ++m) {
      const long row = bm + wr*64 + m*16 + (lane >> 4) * 4;
      #pragma unroll
      for (int j = 0; j < 4; ++j) {
        float v = acc[m][n][j] + bv;
        v = activate<ACT>(v);
        C[(row + j) * ldc + col] = f2b(v);
      }
    }
  }
}

// ---------------- x_proj MFMA: xdbl(f32, ML x 96) = xc @ xp_w^T ----------------
__global__ __launch_bounds__(256) void xproj_mfma(
    const unsigned short* __restrict__ A,   // xc (ML x DI)
    const unsigned short* __restrict__ W,   // xp_wb (96 x DI)
    float* __restrict__ xdbl,               // (ML x 96) f32
    unsigned short* __restrict__ dtr)       // (ML x 64) bf16
{
  __shared__ unsigned short As[64 * 32];
  __shared__ unsigned short Bs[96 * 32];
  const int tid  = threadIdx.x;
  const int lane = tid & 63;
  const int wv   = tid >> 6;
  const long bm  = (long)blockIdx.x * 64;

  const int acol = (tid & 3) * 8;
  const unsigned short* ga  = A + (bm + (tid >> 2)) * DI + acol;
  const unsigned short* gb0 = W + (long)(tid >> 2) * DI + acol;
  const unsigned short* gb1 = W + (long)((tid >> 2) + 64) * DI + acol;
  char* lA = (char*)As;
  char* lB = (char*)Bs;

  const int frow = lane & 15;
  const int fko  = (lane >> 4) * 8;

  f32x4 acc[6];
  #pragma unroll
  for (int n = 0; n < 6; ++n) acc[n] = (f32x4){0.f, 0.f, 0.f, 0.f};

  for (int k0 = 0; k0 < DI; k0 += 32) {
    __syncthreads();
    async16(ga + k0, lA + tid * 16);
    async16(gb0 + k0, lB + tid * 16);
    if (tid < 128) async16(gb1 + k0, lB + 4096 + tid * 16);
    __syncthreads();
    const bfrag a = *reinterpret_cast<const bfrag*>(&As[(wv*16 + frow)*32 + fko]);
    #pragma unroll
    for (int n = 0; n < 6; ++n) {
      const bfrag b = *reinterpret_cast<const bfrag*>(&Bs[(n*16 + frow)*32 + fko]);
      acc[n] = __builtin_amdgcn_mfma_f32_16x16x32_bf16(a, b, acc[n], 0, 0, 0);
    }
  }

  const int r0 = wv*16 + (lane >> 4) * 4;
  #pragma unroll
  for (int n = 0; n < 6; ++n) {
    const int col = n*16 + frow;
    #pragma unroll
    for (int j = 0; j < 4; ++j) {
      const long row = bm + r0 + j;
      const float v = acc[n][j];
      xdbl[row * 96 + col] = v;
      if (n < 4) dtr[row * 64 + col] = f2b(v);
    }
  }
}

// ---------------- f32 -> bf16 convert ----------------
__global__ __launch_bounds__(256) void cvt_bf16(
    const float* __restrict__ in, unsigned short* __restrict__ out, long n4)
{
  const long i = (long)blockIdx.x * 256 + threadIdx.x;
  if (i < n4) {
    const float4 v = reinterpret_cast<const float4*>(in)[i];
    ushort4 o; o.x = f2b(v.x); o.y = f2b(v.y); o.z = f2b(v.z); o.w = f2b(v.w);
    reinterpret_cast<ushort4*>(out)[i] = o;
  }
}

// ---------------- depthwise causal conv (k=4) + silu, bf16 in/out ----------------
__global__ __launch_bounds__(256) void conv_silu(
    const unsigned short* __restrict__ xin,
    const float* __restrict__ w,     // (DI, 4) f32
    const float* __restrict__ bias,  // (DI) f32
    unsigned short* __restrict__ xc)
{
  const int idx = blockIdx.x * 256 + threadIdx.x;
  const int D4 = DI / 4;
  const int d  = (idx % D4) * 4;
  const int bt = idx / D4;
  const int t  = bt & (L - 1);
  const int b  = bt >> 11;
  const float4 w0 = *reinterpret_cast<const float4*>(w + (long)(d+0)*4);
  const float4 w1 = *reinterpret_cast<const float4*>(w + (long)(d+1)*4);
  const float4 w2 = *reinterpret_cast<const float4*>(w + (long)(d+2)*4);
  const float4 w3 = *reinterpret_cast<const float4*>(w + (long)(d+3)*4);
  const float4 bv = *reinterpret_cast<const float4*>(bias + d);
  float a0 = bv.x, a1 = bv.y, a2 = bv.z, a3 = bv.w;
  const float wk0[4] = {w0.x, w0.y, w0.z, w0.w};
  const float wk1[4] = {w1.x, w1.y, w1.z, w1.w};
  const float wk2[4] = {w2.x, w2.y, w2.z, w2.w};
  const float wk3[4] = {w3.x, w3.y, w3.z, w3.w};
  #pragma unroll
  for (int k = 0; k < 4; ++k) {
    const int tt = t - 3 + k;
    if (tt >= 0) {
      const ushort4 xv = *reinterpret_cast<const ushort4*>(xin + ((long)(b * L + tt)) * DI + d);
      a0 = fmaf(wk0[k], b2f(xv.x), a0);
      a1 = fmaf(wk1[k], b2f(xv.y), a1);
      a2 = fmaf(wk2[k], b2f(xv.z), a2);
      a3 = fmaf(wk3[k], b2f(xv.w), a3);
    }
  }
  a0 = a0 / (1.f + expf(-a0));
  a1 = a1 / (1.f + expf(-a1));
  a2 = a2 / (1.f + expf(-a2));
  a3 = a3 / (1.f + expf(-a3));
  ushort4 o; o.x = f2b(a0); o.y = f2b(a1); o.z = f2b(a2); o.w = f2b(a3);
  *reinterpret_cast<ushort4*>(xc + (long)bt * DI + d) = o;
}

// ---------------- chunked selective scan ----------------
__global__ __launch_bounds__(256) void scan_p1(
    const unsigned short* __restrict__ dt,   // (ML, DI) bf16
    const unsigned short* __restrict__ u,    // (ML, DI) bf16
    const float* __restrict__ xdbl,          // (ML, 96): B at 64
    const float* __restrict__ a_log,         // (DI, 16)
    float* __restrict__ hend,                // (Bsz, NCH, 16, DI)
    float* __restrict__ sdt)                 // (Bsz, NCH, DI)
{
  const int bid = blockIdx.x;
  const int dg = bid & 7;
  const int c  = (bid >> 3) & (NCH - 1);
  const int b  = bid >> 8;
  const int d  = dg * 256 + threadIdx.x;
  float A[16];
  #pragma unroll
  for (int q = 0; q < 4; ++q) {
    const float4 al = *reinterpret_cast<const float4*>(a_log + (long)d * 16 + q * 4);
    A[q*4+0] = -__expf(al.x); A[q*4+1] = -__expf(al.y);
    A[q*4+2] = -__expf(al.z); A[q*4+3] = -__expf(al.w);
  }
  float h[16];
  #pragma unroll
  for (int s = 0; s < 16; ++s) h[s] = 0.f;
  float s_dt = 0.f;
  const long row0 = (long)b * L + (long)c * CL;
  for (int t = 0; t < CL; ++t) {
    const long row = row0 + t;
    const float dtv = b2f(dt[row * DI + d]);
    const float uv  = b2f(u [row * DI + d]);
    const float* bp = xdbl + row * 96 + 64;
    const float4 B0 = *reinterpret_cast<const float4*>(bp + 0);
    const float4 B1 = *reinterpret_cast<const float4*>(bp + 4);
    const float4 B2 = *reinterpret_cast<const float4*>(bp + 8);
    const float4 B3 = *reinterpret_cast<const float4*>(bp + 12);
    const float Bv[16] = {B0.x,B0.y,B0.z,B0.w, B1.x,B1.y,B1.z,B1.w,
                          B2.x,B2.y,B2.z,B2.w, B3.x,B3.y,B3.z,B3.w};
    s_dt += dtv;
    const float dtu = dtv * uv;
    #pragma unroll
    for (int s = 0; s < 16; ++s)
      h[s] = fmaf(__expf(dtv * A[s]), h[s], dtu * Bv[s]);
  }
  const long cb = (long)(b * NCH + c);
  #pragma unroll
  for (int s = 0; s < 16; ++s)
    hend[(cb * 16 + s) * DI + d] = h[s];
  sdt[cb * DI + d] = s_dt;
}

__global__ __launch_bounds__(256) void scan_p2(
    float* __restrict__ hend,
    const float* __restrict__ sdt,
    const float* __restrict__ a_log)
{
  const long idx = (long)blockIdx.x * 256 + threadIdx.x;
  const int d = idx & (DI - 1);
  const int s = (idx >> 11) & 15;
  const int b = idx >> 15;
  const float A = -__expf(a_log[(long)d * 16 + s]);
  float h = 0.f;
  for (int c = 0; c < NCH; ++c) {
    const long cb = (long)(b * NCH + c);
    const long off = (cb * 16 + s) * DI + d;
    const float hl = hend[off];
    const float sd = sdt[cb * DI + d];
    hend[off] = h;
    h = fmaf(__expf(A * sd), h, hl);
  }
}

__global__ __launch_bounds__(256) void scan_p3(
    const unsigned short* __restrict__ dt,
    const unsigned short* __restrict__ u,
    const float* __restrict__ xdbl,          // B at 64, C at 80
    const unsigned short* __restrict__ z,
    const float* __restrict__ a_log,
    const float* __restrict__ dpar,
    const float* __restrict__ hinit,
    unsigned short* __restrict__ y)
{
  const int bid = blockIdx.x;
  const int dg = bid & 7;
  const int c  = (bid >> 3) & (NCH - 1);
  const int b  = bid >> 8;
  const int d  = dg * 256 + threadIdx.x;
  float A[16];
  #pragma unroll
  for (int q = 0; q < 4; ++q) {
    const float4 al = *reinterpret_cast<const float4*>(a_log + (long)d * 16 + q * 4);
    A[q*4+0] = -__expf(al.x); A[q*4+1] = -__expf(al.y);
    A[q*4+2] = -__expf(al.z); A[q*4+3] = -__expf(al.w);
  }
  const float Dv = dpar[d];
  const long cb = (long)(b * NCH + c);
  float h[16];
  #pragma unroll
  for (int s = 0; s < 16; ++s)
    h[s] = hinit[(cb * 16 + s) * DI + d];
  const long row0 = (long)b * L + (long)c * CL;
  for (int t = 0; t < CL; ++t) {
    const long row = row0 + t;
    const float dtv = b2f(dt[row * DI + d]);
    const float uv  = b2f(u [row * DI + d]);
    const float* bp = xdbl + row * 96 + 64;
    const float4 B0 = *reinterpret_cast<const float4*>(bp + 0);
    const float4 B1 = *reinterpret_cast<const float4*>(bp + 4);
    const float4 B2 = *reinterpret_cast<const float4*>(bp + 8);
    const float4 B3 = *reinterpret_cast<const float4*>(bp + 12);
    const float4 C0 = *reinterpret_cast<const float4*>(bp + 16);
    const float4 C1 = *reinterpret_cast<const float4*>(bp + 20);
    const float4 C2 = *reinterpret_cast<const float4*>(bp + 24);
    const float4 C3 = *reinterpret_cast<const float4*>(bp + 28);
    const float Bv[16] = {B0.x,B0.y,B0.z,B0.w, B1.x,B1.y,B1.z,B1.w,
                          B2.x,B2.y,B2.z,B2.w, B3.x,B3.y,B3.z,B3.w};
    const float Cv[16] = {C0.x,C0.y,C0.z,C0.w, C1.x,C1.y,C1.z,C1.w,
                          C2.x,C2.y,C2.z,C2.w, C3.x,C3.y,C3.z,C3.w};
    const float dtu = dtv * uv;
    float yv = 0.f;
    #pragma unroll
    for (int s = 0; s < 16; ++s) {
      h[s] = fmaf(__expf(dtv * A[s]), h[s], dtu * Bv[s]);
      yv = fmaf(h[s], Cv[s], yv);
    }
    const float zv = b2f(z[row * DI + d]);
    const float sg = zv / (1.f + __expf(-zv));
    y[row * DI + d] = f2b(fmaf(uv, Dv, yv) * sg);
  }
}

// ---------------- fused add-residual + rmsnorm ----------------
template<bool BIN, bool WBF>
__global__ __launch_bounds__(256) void add_rmsnorm(
    const void* __restrict__ xinp, const float* __restrict__ res,
    const float* __restrict__ w, float* __restrict__ out,
    unsigned short* __restrict__ xb)
{
  const int row = blockIdx.x;
  const int tid = threadIdx.x;
  const long base = (long)row * D;
  float4 v;
  if (BIN) {
    const ushort4 t = *reinterpret_cast<const ushort4*>((const unsigned short*)xinp + base + tid * 4);
    v.x = b2f(t.x); v.y = b2f(t.y); v.z = b2f(t.z); v.w = b2f(t.w);
  } else {
    v = *reinterpret_cast<const float4*>((const float*)xinp + base + tid * 4);
  }
  const float4 r = *reinterpret_cast<const float4*>(res + base + tid * 4);
  v.x += r.x; v.y += r.y; v.z += r.z; v.w += r.w;
  float ss = v.x*v.x + v.y*v.y + v.z*v.z + v.w*v.w;
  #pragma unroll
  for (int m = 1; m < 64; m <<= 1) ss += __shfl_xor(ss, m);
  __shared__ float red[4];
  if ((tid & 63) == 0) red[tid >> 6] = ss;
  __syncthreads();
  const float tot = red[0] + red[1] + red[2] + red[3];
  const float scale = rsqrtf(tot * (1.f / (float)D) + 1.1920929e-07f);
  const float4 wv = *reinterpret_cast<const float4*>(w + tid * 4);
  float4 o;
  o.x = v.x * scale * wv.x;
  o.y = v.y * scale * wv.y;
  o.z = v.z * scale * wv.z;
  o.w = v.w * scale * wv.w;
  *reinterpret_cast<float4*>(out + base + tid * 4) = o;
  if (WBF) {
    ushort4 ob; ob.x = f2b(o.x); ob.y = f2b(o.y); ob.z = f2b(o.z); ob.w = f2b(o.w);
    *reinterpret_cast<ushort4*>(xb + base + tid * 4) = ob;
  }
}

} // namespace

extern "C" void kernel_launch(void* const* d_in, const int* in_sizes, int n_in,
                              void* d_out, int out_size, void* d_ws, size_t ws_size,
                              hipStream_t stream)
{
  const float* x0     = (const float*)d_in[0];
  const float* in_w   = (const float*)d_in[1];
  const float* conv_w = (const float*)d_in[2];
  const float* conv_b = (const float*)d_in[3];
  const float* xp_w   = (const float*)d_in[4];
  const float* dtp_w  = (const float*)d_in[5];
  const float* dtp_b  = (const float*)d_in[6];
  const float* a_log  = (const float*)d_in[7];
  const float* d_par  = (const float*)d_in[8];
  const float* out_w  = (const float*)d_in[9];
  const float* w1     = (const float*)d_in[10];
  const float* b1     = (const float*)d_in[11];
  const float* w2     = (const float*)d_in[12];
  const float* b2     = (const float*)d_in[13];
  const float* ln_w   = (const float*)d_in[14];
  const float* ln2_w  = (const float*)d_in[15];
  float* out = (float*)d_out;

  // ---- workspace layout (~216 MiB total) ----
  char* ws = (char*)d_ws;
  unsigned short* in_wb  = (unsigned short*)(ws);                 // 16 Mi
  unsigned short* out_wb = (unsigned short*)(ws + (16UL  << 20)); //  8 Mi
  unsigned short* w1b    = (unsigned short*)(ws + (24UL  << 20)); //  4 Mi
  unsigned short* w2b    = (unsigned short*)(ws + (28UL  << 20)); //  4 Mi
  unsigned short* xbf    = (unsigned short*)(ws + (32UL  << 20)); // 16 Mi
  unsigned short* zb     = (unsigned short*)(ws + (48UL  << 20)); // 32 Mi
  unsigned short* xc     = (unsigned short*)(ws + (80UL  << 20)); // 32 Mi
  float*          xdbl   = (float*)(ws + (112UL << 20));          //  3 Mi
  float*          sdtb   = (float*)(ws + (115UL << 20));          //  1 Mi
  float*          hendb  = (float*)(ws + (116UL << 20));          // 16 Mi
  unsigned short* xinb   = (unsigned short*)(ws + (132UL << 20)); // 32 Mi (alias: dt)
  unsigned short* dtb    = xinb;
  unsigned short* ybf    = (unsigned short*)(ws + (164UL << 20)); // 32 Mi (alias: hm)
  unsigned short* hm     = ybf;
  unsigned short* mo     = (unsigned short*)(ws + (196UL << 20)); // 16 Mi (alias: t2)
  unsigned short* t2     = mo;
  unsigned short* xp_wb  = (unsigned short*)(ws + (212UL << 20)); // 0.75 Mi
  unsigned short* dtp_wb = (unsigned short*)(ws + (213UL << 20)); // 0.5 Mi
  unsigned short* dtrb   = (unsigned short*)(ws + (214UL << 20)); // 1 Mi: (ML,64) bf16

  const dim3 blk(256);
  const dim3 blk5(512);

  // one-time f32 -> bf16 conversions (weights + layer-0 input)
  cvt_bf16<<<dim3((2L*2*DI*D/4 + 255)/256), blk, 0, stream>>>(in_w,  in_wb,  2L*2*DI*D/4);
  cvt_bf16<<<dim3((2L*D*DI/4   + 255)/256), blk, 0, stream>>>(out_w, out_wb, 2L*D*DI/4);
  cvt_bf16<<<dim3((2L*D*D/4    + 255)/256), blk, 0, stream>>>(w1,    w1b,    2L*D*D/4);
  cvt_bf16<<<dim3((2L*D*D/4    + 255)/256), blk, 0, stream>>>(w2,    w2b,    2L*D*D/4);
  cvt_bf16<<<dim3((2L*96*DI/4  + 255)/256), blk, 0, stream>>>(xp_w,  xp_wb,  2L*96*DI/4);
  cvt_bf16<<<dim3((2L*DI*DTR/4 + 255)/256), blk, 0, stream>>>(dtp_w, dtp_wb, 2L*DI*DTR/4);
  cvt_bf16<<<dim3(((long)ML*D/4+ 255)/256), blk, 0, stream>>>(x0,    xbf,    (long)ML*D/4);

  const float* xcur = x0;
  for (int layer = 0; layer < 2; ++layer) {
    const long lo = (long)layer;
    const unsigned short* Winb = in_wb + lo * 2 * DI * D;
    // 1. [x_in | z] = x @ in_proj^T  (256-tile, N=4096, K=1024, split epilogue)
    gemm2<0,false,256,true><<<dim3(16, 32), blk5, 0, stream>>>(
        xbf, D, Winb, D, nullptr, xinb, zb, DI, D);
    // 2. xc = silu(causal_conv(x_in))
    conv_silu<<<dim3((long)ML*DI/4/256), blk, 0, stream>>>(
        xinb, conv_w + lo*DI*4, conv_b + lo*DI, xc);
    // 3. xdbl = xc @ x_proj^T  (MFMA, N=96, K=2048) + bf16 dt cols
    xproj_mfma<<<dim3(ML/64), blk, 0, stream>>>(
        xc, xp_wb + lo*96*DI, xdbl, dtrb);
    // 4. dt = softplus(dtr @ dt_proj^T + b)  (MFMA 128-tile, N=2048, K=64)
    gemm_mfma<3,true><<<dim3(DI/128, ML/128), blk, 0, stream>>>(
        dtrb, DTR, dtp_wb + lo*DI*DTR, DTR, dtp_b + lo*DI, dtb, DI, DTR);
    // 5. chunked selective scan -> ybf bf16
    scan_p1<<<dim3(Bsz*NCH*(DI/256)), blk, 0, stream>>>(
        dtb, xc, xdbl, a_log + lo*DI*DSTATE, hendb, sdtb);
    scan_p2<<<dim3(Bsz*DSTATE*DI/256), blk, 0, stream>>>(
        hendb, sdtb, a_log + lo*DI*DSTATE);
    scan_p3<<<dim3(Bsz*NCH*(DI/256)), blk, 0, stream>>>(
        dtb, xc, xdbl, zb, a_log + lo*DI*DSTATE, d_par + lo*DI, hendb, ybf);
    // 6. mo = y @ out_proj^T  (256-tile BN=128, N=1024, K=2048)
    gemm2<0,false,128,false><<<dim3(8, 32), blk5, 0, stream>>>(
        ybf, DI, out_wb + lo*D*DI, DI, nullptr, mo, nullptr, D, DI);
    // 7. hm = gelu(mo @ w1^T + b1)  (256-tile, N=2048, K=1024)
    gemm2<2,true,256,false><<<dim3(8, 32), blk5, 0, stream>>>(
        mo, D, w1b, D, b1, hm, nullptr, 2*D, D);
    // 8. t2 = gelu(hm @ w2^T + b2)  (256-tile BN=128, N=1024, K=2048)
    gemm2<2,true,128,false><<<dim3(8, 32), blk5, 0, stream>>>(
        hm, 2*D, w2b, 2*D, b2, t2, nullptr, D, 2*D);
    // 9. x = rmsnorm(t2 + residual) -> out (f32) + xbf (bf16)
    add_rmsnorm<true,true><<<dim3(ML), blk, 0, stream>>>(t2, xcur, ln_w, out, xbf);
    xcur = out;
  }
  // final: rmsnorm(x + residual2)
  add_rmsnorm<false,false><<<dim3(ML), blk, 0, stream>>>(out, x0, ln2_w, out, nullptr);
}

// Round 7
// 1113.525 us; speedup vs baseline: 7.6663x; 1.0329x over previous
//
#include <hip/hip_runtime.h>
#include <math.h>

namespace {

constexpr int Bsz = 4;
constexpr int L   = 2048;
constexpr int D   = 1024;
constexpr int DI  = 2048;
constexpr int DSTATE = 16;
constexpr int DTR = 64;
constexpr int ML  = Bsz * L; // 8192 rows
constexpr int NCH = 32;      // chunks per sequence
constexpr int CL  = 64;      // chunk length

typedef __attribute__((ext_vector_type(8))) short bfrag;   // 8 bf16 (4 VGPRs)
typedef __attribute__((ext_vector_type(4))) float f32x4;

// ---- bf16 bit helpers (RNE) ----
__device__ __forceinline__ unsigned short f2b(float f) {
  union { float f; unsigned int u; } c; c.f = f;
  unsigned int u = c.u;
  unsigned int r = (u + 0x7fffu + ((u >> 16) & 1u)) >> 16;
  return (unsigned short)r;
}
__device__ __forceinline__ float b2f(unsigned short h) {
  union { unsigned int u; float f; } c; c.u = ((unsigned int)h) << 16;
  return c.f;
}

// ---- async global->LDS 16B ----
__device__ __forceinline__ void async16(const void* g, void* l) {
  __builtin_amdgcn_global_load_lds(
      (const __attribute__((address_space(1))) void*)g,
      (__attribute__((address_space(3))) void*)l, 16, 0, 0);
}

// ---------------- activations ----------------
template<int ACT>
__device__ __forceinline__ float activate(float x) {
  if (ACT == 1) { return x / (1.f + expf(-x)); }
  if (ACT == 2) { return 0.5f * x * (1.f + erff(x * 0.7071067811865475f)); }
  if (ACT == 3) { return (x > 20.f) ? x : log1pf(expf(x)); }
  return x;
}

// ---------------- 256-tile counted-vmcnt bf16 MFMA GEMM ----------------
// C = act(A @ W^T + bias).  A: (M x K) bf16 stride lda; W: (N x K) bf16 stride ldw.
// BM=256, BN template (256/128), BK=64, 512 threads = 8 waves (2M x 4N).
// Double-buffered LDS; raw s_barrier + counted s_waitcnt vmcnt(NL) so the
// in-flight stage always has a full iteration of MFMA over it (T3/T4/T5).
// MFMA operands SWAPPED (mfma(b,a)) so lane j-regs = 4 consecutive cols ->
// packed ushort4 stores (kills 2-byte write amplification).
// SPLIT: cols [0,2048) -> C0, [2048,4096) -> C1 (both ldc).
template<int ACT, bool HAS_BIAS, int BN, bool SPLIT>
__global__ __launch_bounds__(512) void gemm2(
    const unsigned short* __restrict__ A, long lda,
    const unsigned short* __restrict__ W, long ldw,
    const float* __restrict__ bias,
    unsigned short* __restrict__ C0,
    unsigned short* __restrict__ C1,
    long ldc, int K)
{
  constexpr int NB   = BN / 64;      // n-frags per wave (4 or 2)
  constexpr int ABUF = 256 * 64;     // elems per A buffer
  constexpr int BBUF = BN * 64;
  constexpr int NLA  = 4;            // A global_load_lds per thread per stage
  constexpr int NLB  = NB;           // B loads per thread per stage
  constexpr int NL   = NLA + NLB;
  __shared__ unsigned short lds[2 * ABUF + 2 * BBUF];

  const int tid  = threadIdx.x;
  const int lane = tid & 63;
  const int wid  = tid >> 6;
  const int wr   = wid >> 2;         // 0..1
  const int wc   = wid & 3;          // 0..3
  const int frow = lane & 15;
  const int klg  = lane >> 4;

  // bijective XCD swizzle (nwg % 8 == 0 for all our grids)
  const int gx = gridDim.x;
  int id = blockIdx.y * gx + blockIdx.x;
  const int q = (gx * gridDim.y) >> 3;
  id = (id & 7) * q + (id >> 3);
  const int bx = id % gx;
  const int by = id / gx;
  const long bm = (long)by * 256;
  const long bn = (long)bx * BN;

  unsigned short* Cb;
  long cbase;
  if (SPLIT) {
    if (bn < 2048) { Cb = C0; cbase = bn; }
    else           { Cb = C1; cbase = bn - 2048; }
  } else { Cb = C0; cbase = bn; }

  f32x4 acc[8][NB];
  #pragma unroll
  for (int m = 0; m < 8; ++m)
    #pragma unroll
    for (int n = 0; n < NB; ++n)
      acc[m][n] = (f32x4){0.f, 0.f, 0.f, 0.f};

  auto stage = [&](int kt, int p) {
    const long kcol = (long)kt * 64;
    #pragma unroll
    for (int l = 0; l < NLA; ++l) {                // A loads
      const int idx = tid + l * 512;               // [0, 2048)
      const int row = idx >> 3;                    // [0, 256)
      const int ch  = (idx & 7) ^ (row & 7);
      async16(A + (bm + row) * lda + kcol + ch * 8,
              &lds[p * ABUF + idx * 8]);
    }
    #pragma unroll
    for (int l = 0; l < NLB; ++l) {                // B loads
      const int idx = tid + l * 512;               // [0, BN*8)
      const int row = idx >> 3;                    // [0, BN)
      const int ch  = (idx & 7) ^ (row & 7);
      async16(W + (bn + row) * ldw + kcol + ch * 8,
              &lds[2 * ABUF + p * BBUF + idx * 8]);
    }
  };

  const int NT = K >> 6;
  stage(0, 0);
  stage(1, 1);
  asm volatile("s_waitcnt vmcnt(%0)" :: "n"(NL) : "memory");  // stage 0 done
  __builtin_amdgcn_sched_barrier(0);
  __builtin_amdgcn_s_barrier();

  for (int kt = 0; kt < NT; ++kt) {
    const unsigned short* Ab = &lds[(kt & 1) * ABUF];
    const unsigned short* Bb = &lds[2 * ABUF + (kt & 1) * BBUF];
    __builtin_amdgcn_s_setprio(1);
    #pragma unroll
    for (int kk = 0; kk < 2; ++kk) {
      bfrag av[8], bv[NB];
      #pragma unroll
      for (int m = 0; m < 8; ++m) {
        const int r  = wr * 128 + m * 16 + frow;
        const int ch = (kk * 4 + klg) ^ (r & 7);
        av[m] = *reinterpret_cast<const bfrag*>(&Ab[r * 64 + ch * 8]);
      }
      #pragma unroll
      for (int n = 0; n < NB; ++n) {
        const int r  = wc * (BN / 4) + n * 16 + frow;
        const int ch = (kk * 4 + klg) ^ (r & 7);
        bv[n] = *reinterpret_cast<const bfrag*>(&Bb[r * 64 + ch * 8]);
      }
      #pragma unroll
      for (int m = 0; m < 8; ++m)
        #pragma unroll
        for (int n = 0; n < NB; ++n)
          acc[m][n] = __builtin_amdgcn_mfma_f32_16x16x32_bf16(bv[n], av[m], acc[m][n], 0, 0, 0);
    }
    __builtin_amdgcn_s_setprio(0);
    if (kt + 1 == NT) break;                 // last tile: no more LDS work
    __builtin_amdgcn_sched_barrier(0);
    __builtin_amdgcn_s_barrier();            // all waves done reading buf kt
    if (kt + 2 < NT) {
      stage(kt + 2, kt & 1);                 // overwrite buf kt
      asm volatile("s_waitcnt vmcnt(%0)" :: "n"(NL) : "memory");  // kt+1 done
    } else {
      asm volatile("s_waitcnt vmcnt(0)" ::: "memory");            // tail drain
    }
    __builtin_amdgcn_sched_barrier(0);
    __builtin_amdgcn_s_barrier();            // publish buf kt+1
  }

  // epilogue (swapped mapping): row = ...+frow, cols = ...+klg*4+{0..3}
  #pragma unroll
  for (int n = 0; n < NB; ++n) {
    const long coff = wc * (BN / 4) + n * 16 + klg * 4;
    float4 b4 = make_float4(0.f, 0.f, 0.f, 0.f);
    if (HAS_BIAS) b4 = *reinterpret_cast<const float4*>(&bias[bn + coff]);
    #pragma unroll
    for (int m = 0; m < 8; ++m) {
      const long row = bm + wr * 128 + m * 16 + frow;
      const float v0 = activate<ACT>(acc[m][n][0] + b4.x);
      const float v1 = activate<ACT>(acc[m][n][1] + b4.y);
      const float v2 = activate<ACT>(acc[m][n][2] + b4.z);
      const float v3 = activate<ACT>(acc[m][n][3] + b4.w);
      ushort4 o; o.x = f2b(v0); o.y = f2b(v1); o.z = f2b(v2); o.w = f2b(v3);
      *reinterpret_cast<ushort4*>(&Cb[row * ldc + cbase + coff]) = o;
    }
  }
}

// ---------------- 128-tile MFMA GEMM (dt_proj: K=64, write-bound) ----------------
template<int ACT, bool HAS_BIAS>
__global__ __launch_bounds__(256) void gemm_mfma(
    const unsigned short* __restrict__ A, long lda,
    const unsigned short* __restrict__ W, long ldw,
    const float* __restrict__ bias,
    unsigned short* __restrict__ C, long ldc,
    int K)
{
  __shared__ unsigned short As[128 * 32];
  __shared__ unsigned short Bs[128 * 32];
  const int tid  = threadIdx.x;
  const int lane = tid & 63;
  const int w    = tid >> 6;
  const int wr   = w >> 1, wc = w & 1;
  const long bm = (long)blockIdx.y * 128;
  const long bn = (long)blockIdx.x * 128;

  const int srow = tid >> 2;
  const int scol = (tid & 3) * 8;
  const unsigned short* ga0 = A + (bm + srow)      * lda + scol;
  const unsigned short* ga1 = A + (bm + 64 + srow) * lda + scol;
  const unsigned short* gb0 = W + (bn + srow)      * ldw + scol;
  const unsigned short* gb1 = W + (bn + 64 + srow) * ldw + scol;
  char* lA = (char*)As;
  char* lB = (char*)Bs;
  const int loff = tid * 16;

  const int frow = lane & 15;
  const int klg  = lane >> 4;
  const int fko  = klg * 8;

  f32x4 acc[4][4];
  #pragma unroll
  for (int m = 0; m < 4; ++m)
    #pragma unroll
    for (int n = 0; n < 4; ++n)
      acc[m][n] = (f32x4){0.f, 0.f, 0.f, 0.f};

  for (int k0 = 0; k0 < K; k0 += 32) {
    __syncthreads();
    async16(ga0 + k0, lA + loff);
    async16(ga1 + k0, lA + 4096 + loff);
    async16(gb0 + k0, lB + loff);
    async16(gb1 + k0, lB + 4096 + loff);
    __syncthreads();
    bfrag a[4], b[4];
    #pragma unroll
    for (int m = 0; m < 4; ++m)
      a[m] = *reinterpret_cast<const bfrag*>(&As[(wr*64 + m*16 + frow)*32 + fko]);
    #pragma unroll
    for (int n = 0; n < 4; ++n)
      b[n] = *reinterpret_cast<const bfrag*>(&Bs[(wc*64 + n*16 + frow)*32 + fko]);
    #pragma unroll
    for (int m = 0; m < 4; ++m)
      #pragma unroll
      for (int n = 0; n < 4; ++n)
        acc[m][n] = __builtin_amdgcn_mfma_f32_16x16x32_bf16(b[n], a[m], acc[m][n], 0, 0, 0);
  }

  #pragma unroll
  for (int n = 0; n < 4; ++n) {
    const long col = bn + wc*64 + n*16 + klg*4;
    float4 b4 = make_float4(0.f, 0.f, 0.f, 0.f);
    if (HAS_BIAS) b4 = *reinterpret_cast<const float4*>(&bias[col]);
    #pragma unroll
    for (int m = 0; m < 4; ++m) {
      const long row = bm + wr*64 + m*16 + frow;
      const float v0 = activate<ACT>(acc[m][n][0] + b4.x);
      const float v1 = activate<ACT>(acc[m][n][1] + b4.y);
      const float v2 = activate<ACT>(acc[m][n][2] + b4.z);
      const float v3 = activate<ACT>(acc[m][n][3] + b4.w);
      ushort4 o; o.x = f2b(v0); o.y = f2b(v1); o.z = f2b(v2); o.w = f2b(v3);
      *reinterpret_cast<ushort4*>(&C[row * ldc + col]) = o;
    }
  }
}

// ---------------- x_proj MFMA: xdbl(f32, ML x 96) = xc @ xp_w^T ----------------
__global__ __launch_bounds__(256) void xproj_mfma(
    const unsigned short* __restrict__ A,   // xc (ML x DI)
    const unsigned short* __restrict__ W,   // xp_wb (96 x DI)
    float* __restrict__ xdbl,               // (ML x 96) f32
    unsigned short* __restrict__ dtr)       // (ML x 64) bf16
{
  __shared__ unsigned short As[64 * 32];
  __shared__ unsigned short Bs[96 * 32];
  const int tid  = threadIdx.x;
  const int lane = tid & 63;
  const int wv   = tid >> 6;
  const long bm  = (long)blockIdx.x * 64;

  const int acol = (tid & 3) * 8;
  const unsigned short* ga  = A + (bm + (tid >> 2)) * DI + acol;
  const unsigned short* gb0 = W + (long)(tid >> 2) * DI + acol;
  const unsigned short* gb1 = W + (long)((tid >> 2) + 64) * DI + acol;
  char* lA = (char*)As;
  char* lB = (char*)Bs;

  const int frow = lane & 15;
  const int klg  = lane >> 4;
  const int fko  = klg * 8;

  f32x4 acc[6];
  #pragma unroll
  for (int n = 0; n < 6; ++n) acc[n] = (f32x4){0.f, 0.f, 0.f, 0.f};

  for (int k0 = 0; k0 < DI; k0 += 32) {
    __syncthreads();
    async16(ga + k0, lA + tid * 16);
    async16(gb0 + k0, lB + tid * 16);
    if (tid < 128) async16(gb1 + k0, lB + 4096 + tid * 16);
    __syncthreads();
    const bfrag a = *reinterpret_cast<const bfrag*>(&As[(wv*16 + frow)*32 + fko]);
    #pragma unroll
    for (int n = 0; n < 6; ++n) {
      const bfrag b = *reinterpret_cast<const bfrag*>(&Bs[(n*16 + frow)*32 + fko]);
      acc[n] = __builtin_amdgcn_mfma_f32_16x16x32_bf16(b, a, acc[n], 0, 0, 0);
    }
  }

  const long row = bm + wv*16 + frow;
  #pragma unroll
  for (int n = 0; n < 6; ++n) {
    const int col = n*16 + klg*4;
    float4 v; v.x = acc[n][0]; v.y = acc[n][1]; v.z = acc[n][2]; v.w = acc[n][3];
    *reinterpret_cast<float4*>(&xdbl[row * 96 + col]) = v;
    if (n < 4) {
      ushort4 o; o.x = f2b(v.x); o.y = f2b(v.y); o.z = f2b(v.z); o.w = f2b(v.w);
      *reinterpret_cast<ushort4*>(&dtr[row * 64 + col]) = o;
    }
  }
}

// ---------------- f32 -> bf16 convert ----------------
__global__ __launch_bounds__(256) void cvt_bf16(
    const float* __restrict__ in, unsigned short* __restrict__ out, long n4)
{
  const long i = (long)blockIdx.x * 256 + threadIdx.x;
  if (i < n4) {
    const float4 v = reinterpret_cast<const float4*>(in)[i];
    ushort4 o; o.x = f2b(v.x); o.y = f2b(v.y); o.z = f2b(v.z); o.w = f2b(v.w);
    reinterpret_cast<ushort4*>(out)[i] = o;
  }
}

// ---------------- depthwise causal conv (k=4) + silu, bf16 in/out ----------------
__global__ __launch_bounds__(256) void conv_silu(
    const unsigned short* __restrict__ xin,
    const float* __restrict__ w,     // (DI, 4) f32
    const float* __restrict__ bias,  // (DI) f32
    unsigned short* __restrict__ xc)
{
  const int idx = blockIdx.x * 256 + threadIdx.x;
  const int D4 = DI / 4;
  const int d  = (idx % D4) * 4;
  const int bt = idx / D4;
  const int t  = bt & (L - 1);
  const int b  = bt >> 11;
  const float4 w0 = *reinterpret_cast<const float4*>(w + (long)(d+0)*4);
  const float4 w1 = *reinterpret_cast<const float4*>(w + (long)(d+1)*4);
  const float4 w2 = *reinterpret_cast<const float4*>(w + (long)(d+2)*4);
  const float4 w3 = *reinterpret_cast<const float4*>(w + (long)(d+3)*4);
  const float4 bv = *reinterpret_cast<const float4*>(bias + d);
  float a0 = bv.x, a1 = bv.y, a2 = bv.z, a3 = bv.w;
  const float wk0[4] = {w0.x, w0.y, w0.z, w0.w};
  const float wk1[4] = {w1.x, w1.y, w1.z, w1.w};
  const float wk2[4] = {w2.x, w2.y, w2.z, w2.w};
  const float wk3[4] = {w3.x, w3.y, w3.z, w3.w};
  #pragma unroll
  for (int k = 0; k < 4; ++k) {
    const int tt = t - 3 + k;
    if (tt >= 0) {
      const ushort4 xv = *reinterpret_cast<const ushort4*>(xin + ((long)(b * L + tt)) * DI + d);
      a0 = fmaf(wk0[k], b2f(xv.x), a0);
      a1 = fmaf(wk1[k], b2f(xv.y), a1);
      a2 = fmaf(wk2[k], b2f(xv.z), a2);
      a3 = fmaf(wk3[k], b2f(xv.w), a3);
    }
  }
  a0 = a0 / (1.f + expf(-a0));
  a1 = a1 / (1.f + expf(-a1));
  a2 = a2 / (1.f + expf(-a2));
  a3 = a3 / (1.f + expf(-a3));
  ushort4 o; o.x = f2b(a0); o.y = f2b(a1); o.z = f2b(a2); o.w = f2b(a3);
  *reinterpret_cast<ushort4*>(xc + (long)bt * DI + d) = o;
}

// ---------------- chunked selective scan ----------------
__global__ __launch_bounds__(256) void scan_p1(
    const unsigned short* __restrict__ dt,   // (ML, DI) bf16
    const unsigned short* __restrict__ u,    // (ML, DI) bf16
    const float* __restrict__ xdbl,          // (ML, 96): B at 64
    const float* __restrict__ a_log,         // (DI, 16)
    float* __restrict__ hend,                // (Bsz, NCH, 16, DI)
    float* __restrict__ sdt)                 // (Bsz, NCH, DI)
{
  const int bid = blockIdx.x;
  const int dg = bid & 7;
  const int c  = (bid >> 3) & (NCH - 1);
  const int b  = bid >> 8;
  const int d  = dg * 256 + threadIdx.x;
  float A[16];
  #pragma unroll
  for (int q = 0; q < 4; ++q) {
    const float4 al = *reinterpret_cast<const float4*>(a_log + (long)d * 16 + q * 4);
    A[q*4+0] = -__expf(al.x); A[q*4+1] = -__expf(al.y);
    A[q*4+2] = -__expf(al.z); A[q*4+3] = -__expf(al.w);
  }
  float h[16];
  #pragma unroll
  for (int s = 0; s < 16; ++s) h[s] = 0.f;
  float s_dt = 0.f;
  const long row0 = (long)b * L + (long)c * CL;
  for (int t = 0; t < CL; ++t) {
    const long row = row0 + t;
    const float dtv = b2f(dt[row * DI + d]);
    const float uv  = b2f(u [row * DI + d]);
    const float* bp = xdbl + row * 96 + 64;
    const float4 B0 = *reinterpret_cast<const float4*>(bp + 0);
    const float4 B1 = *reinterpret_cast<const float4*>(bp + 4);
    const float4 B2 = *reinterpret_cast<const float4*>(bp + 8);
    const float4 B3 = *reinterpret_cast<const float4*>(bp + 12);
    const float Bv[16] = {B0.x,B0.y,B0.z,B0.w, B1.x,B1.y,B1.z,B1.w,
                          B2.x,B2.y,B2.z,B2.w, B3.x,B3.y,B3.z,B3.w};
    s_dt += dtv;
    const float dtu = dtv * uv;
    #pragma unroll
    for (int s = 0; s < 16; ++s)
      h[s] = fmaf(__expf(dtv * A[s]), h[s], dtu * Bv[s]);
  }
  const long cb = (long)(b * NCH + c);
  #pragma unroll
  for (int s = 0; s < 16; ++s)
    hend[(cb * 16 + s) * DI + d] = h[s];
  sdt[cb * DI + d] = s_dt;
}

__global__ __launch_bounds__(256) void scan_p2(
    float* __restrict__ hend,
    const float* __restrict__ sdt,
    const float* __restrict__ a_log)
{
  const long idx = (long)blockIdx.x * 256 + threadIdx.x;
  const int d = idx & (DI - 1);
  const int s = (idx >> 11) & 15;
  const int b = idx >> 15;
  const float A = -__expf(a_log[(long)d * 16 + s]);
  float h = 0.f;
  for (int c = 0; c < NCH; ++c) {
    const long cb = (long)(b * NCH + c);
    const long off = (cb * 16 + s) * DI + d;
    const float hl = hend[off];
    const float sd = sdt[cb * DI + d];
    hend[off] = h;
    h = fmaf(__expf(A * sd), h, hl);
  }
}

__global__ __launch_bounds__(256) void scan_p3(
    const unsigned short* __restrict__ dt,
    const unsigned short* __restrict__ u,
    const float* __restrict__ xdbl,          // B at 64, C at 80
    const unsigned short* __restrict__ z,
    const float* __restrict__ a_log,
    const float* __restrict__ dpar,
    const float* __restrict__ hinit,
    unsigned short* __restrict__ y)
{
  const int bid = blockIdx.x;
  const int dg = bid & 7;
  const int c  = (bid >> 3) & (NCH - 1);
  const int b  = bid >> 8;
  const int d  = dg * 256 + threadIdx.x;
  float A[16];
  #pragma unroll
  for (int q = 0; q < 4; ++q) {
    const float4 al = *reinterpret_cast<const float4*>(a_log + (long)d * 16 + q * 4);
    A[q*4+0] = -__expf(al.x); A[q*4+1] = -__expf(al.y);
    A[q*4+2] = -__expf(al.z); A[q*4+3] = -__expf(al.w);
  }
  const float Dv = dpar[d];
  const long cb = (long)(b * NCH + c);
  float h[16];
  #pragma unroll
  for (int s = 0; s < 16; ++s)
    h[s] = hinit[(cb * 16 + s) * DI + d];
  const long row0 = (long)b * L + (long)c * CL;
  for (int t = 0; t < CL; ++t) {
    const long row = row0 + t;
    const float dtv = b2f(dt[row * DI + d]);
    const float uv  = b2f(u [row * DI + d]);
    const float* bp = xdbl + row * 96 + 64;
    const float4 B0 = *reinterpret_cast<const float4*>(bp + 0);
    const float4 B1 = *reinterpret_cast<const float4*>(bp + 4);
    const float4 B2 = *reinterpret_cast<const float4*>(bp + 8);
    const float4 B3 = *reinterpret_cast<const float4*>(bp + 12);
    const float4 C0 = *reinterpret_cast<const float4*>(bp + 16);
    const float4 C1 = *reinterpret_cast<const float4*>(bp + 20);
    const float4 C2 = *reinterpret_cast<const float4*>(bp + 24);
    const float4 C3 = *reinterpret_cast<const float4*>(bp + 28);
    const float Bv[16] = {B0.x,B0.y,B0.z,B0.w, B1.x,B1.y,B1.z,B1.w,
                          B2.x,B2.y,B2.z,B2.w, B3.x,B3.y,B3.z,B3.w};
    const float Cv[16] = {C0.x,C0.y,C0.z,C0.w, C1.x,C1.y,C1.z,C1.w,
                          C2.x,C2.y,C2.z,C2.w, C3.x,C3.y,C3.z,C3.w};
    const float dtu = dtv * uv;
    float yv = 0.f;
    #pragma unroll
    for (int s = 0; s < 16; ++s) {
      h[s] = fmaf(__expf(dtv * A[s]), h[s], dtu * Bv[s]);
      yv = fmaf(h[s], Cv[s], yv);
    }
    const float zv = b2f(z[row * DI + d]);
    const float sg = zv / (1.f + __expf(-zv));
    y[row * DI + d] = f2b(fmaf(uv, Dv, yv) * sg);
  }
}

// ---------------- fused add-residual + rmsnorm ----------------
template<bool BIN, bool WBF>
__global__ __launch_bounds__(256) void add_rmsnorm(
    const void* __restrict__ xinp, const float* __restrict__ res,
    const float* __restrict__ w, float* __restrict__ out,
    unsigned short* __restrict__ xb)
{
  const int row = blockIdx.x;
  const int tid = threadIdx.x;
  const long base = (long)row * D;
  float4 v;
  if (BIN) {
    const ushort4 t = *reinterpret_cast<const ushort4*>((const unsigned short*)xinp + base + tid * 4);
    v.x = b2f(t.x); v.y = b2f(t.y); v.z = b2f(t.z); v.w = b2f(t.w);
  } else {
    v = *reinterpret_cast<const float4*>((const float*)xinp + base + tid * 4);
  }
  const float4 r = *reinterpret_cast<const float4*>(res + base + tid * 4);
  v.x += r.x; v.y += r.y; v.z += r.z; v.w += r.w;
  float ss = v.x*v.x + v.y*v.y + v.z*v.z + v.w*v.w;
  #pragma unroll
  for (int m = 1; m < 64; m <<= 1) ss += __shfl_xor(ss, m);
  __shared__ float red[4];
  if ((tid & 63) == 0) red[tid >> 6] = ss;
  __syncthreads();
  const float tot = red[0] + red[1] + red[2] + red[3];
  const float scale = rsqrtf(tot * (1.f / (float)D) + 1.1920929e-07f);
  const float4 wv = *reinterpret_cast<const float4*>(w + tid * 4);
  float4 o;
  o.x = v.x * scale * wv.x;
  o.y = v.y * scale * wv.y;
  o.z = v.z * scale * wv.z;
  o.w = v.w * scale * wv.w;
  *reinterpret_cast<float4*>(out + base + tid * 4) = o;
  if (WBF) {
    ushort4 ob; ob.x = f2b(o.x); ob.y = f2b(o.y); ob.z = f2b(o.z); ob.w = f2b(o.w);
    *reinterpret_cast<ushort4*>(xb + base + tid * 4) = ob;
  }
}

} // namespace

extern "C" void kernel_launch(void* const* d_in, const int* in_sizes, int n_in,
                              void* d_out, int out_size, void* d_ws, size_t ws_size,
                              hipStream_t stream)
{
  const float* x0     = (const float*)d_in[0];
  const float* in_w   = (const float*)d_in[1];
  const float* conv_w = (const float*)d_in[2];
  const float* conv_b = (const float*)d_in[3];
  const float* xp_w   = (const float*)d_in[4];
  const float* dtp_w  = (const float*)d_in[5];
  const float* dtp_b  = (const float*)d_in[6];
  const float* a_log  = (const float*)d_in[7];
  const float* d_par  = (const float*)d_in[8];
  const float* out_w  = (const float*)d_in[9];
  const float* w1     = (const float*)d_in[10];
  const float* b1     = (const float*)d_in[11];
  const float* w2     = (const float*)d_in[12];
  const float* b2     = (const float*)d_in[13];
  const float* ln_w   = (const float*)d_in[14];
  const float* ln2_w  = (const float*)d_in[15];
  float* out = (float*)d_out;

  // ---- workspace layout (~216 MiB total) ----
  char* ws = (char*)d_ws;
  unsigned short* in_wb  = (unsigned short*)(ws);                 // 16 Mi
  unsigned short* out_wb = (unsigned short*)(ws + (16UL  << 20)); //  8 Mi
  unsigned short* w1b    = (unsigned short*)(ws + (24UL  << 20)); //  4 Mi
  unsigned short* w2b    = (unsigned short*)(ws + (28UL  << 20)); //  4 Mi
  unsigned short* xbf    = (unsigned short*)(ws + (32UL  << 20)); // 16 Mi
  unsigned short* zb     = (unsigned short*)(ws + (48UL  << 20)); // 32 Mi
  unsigned short* xc     = (unsigned short*)(ws + (80UL  << 20)); // 32 Mi
  float*          xdbl   = (float*)(ws + (112UL << 20));          //  3 Mi
  float*          sdtb   = (float*)(ws + (115UL << 20));          //  1 Mi
  float*          hendb  = (float*)(ws + (116UL << 20));          // 16 Mi
  unsigned short* xinb   = (unsigned short*)(ws + (132UL << 20)); // 32 Mi (alias: dt)
  unsigned short* dtb    = xinb;
  unsigned short* ybf    = (unsigned short*)(ws + (164UL << 20)); // 32 Mi (alias: hm)
  unsigned short* hm     = ybf;
  unsigned short* mo     = (unsigned short*)(ws + (196UL << 20)); // 16 Mi (alias: t2)
  unsigned short* t2     = mo;
  unsigned short* xp_wb  = (unsigned short*)(ws + (212UL << 20)); // 0.75 Mi
  unsigned short* dtp_wb = (unsigned short*)(ws + (213UL << 20)); // 0.5 Mi
  unsigned short* dtrb   = (unsigned short*)(ws + (214UL << 20)); // 1 Mi: (ML,64) bf16

  const dim3 blk(256);
  const dim3 blk5(512);

  // one-time f32 -> bf16 conversions (weights + layer-0 input)
  cvt_bf16<<<dim3((2L*2*DI*D/4 + 255)/256), blk, 0, stream>>>(in_w,  in_wb,  2L*2*DI*D/4);
  cvt_bf16<<<dim3((2L*D*DI/4   + 255)/256), blk, 0, stream>>>(out_w, out_wb, 2L*D*DI/4);
  cvt_bf16<<<dim3((2L*D*D/4    + 255)/256), blk, 0, stream>>>(w1,    w1b,    2L*D*D/4);
  cvt_bf16<<<dim3((2L*D*D/4    + 255)/256), blk, 0, stream>>>(w2,    w2b,    2L*D*D/4);
  cvt_bf16<<<dim3((2L*96*DI/4  + 255)/256), blk, 0, stream>>>(xp_w,  xp_wb,  2L*96*DI/4);
  cvt_bf16<<<dim3((2L*DI*DTR/4 + 255)/256), blk, 0, stream>>>(dtp_w, dtp_wb, 2L*DI*DTR/4);
  cvt_bf16<<<dim3(((long)ML*D/4+ 255)/256), blk, 0, stream>>>(x0,    xbf,    (long)ML*D/4);

  const float* xcur = x0;
  for (int layer = 0; layer < 2; ++layer) {
    const long lo = (long)layer;
    const unsigned short* Winb = in_wb + lo * 2 * DI * D;
    // 1. [x_in | z] = x @ in_proj^T  (256-tile, N=4096, K=1024, split epilogue)
    gemm2<0,false,256,true><<<dim3(16, 32), blk5, 0, stream>>>(
        xbf, D, Winb, D, nullptr, xinb, zb, DI, D);
    // 2. xc = silu(causal_conv(x_in))
    conv_silu<<<dim3((long)ML*DI/4/256), blk, 0, stream>>>(
        xinb, conv_w + lo*DI*4, conv_b + lo*DI, xc);
    // 3. xdbl = xc @ x_proj^T  (MFMA, N=96, K=2048) + bf16 dt cols
    xproj_mfma<<<dim3(ML/64), blk, 0, stream>>>(
        xc, xp_wb + lo*96*DI, xdbl, dtrb);
    // 4. dt = softplus(dtr @ dt_proj^T + b)  (MFMA 128-tile, N=2048, K=64)
    gemm_mfma<3,true><<<dim3(DI/128, ML/128), blk, 0, stream>>>(
        dtrb, DTR, dtp_wb + lo*DI*DTR, DTR, dtp_b + lo*DI, dtb, DI, DTR);
    // 5. chunked selective scan -> ybf bf16
    scan_p1<<<dim3(Bsz*NCH*(DI/256)), blk, 0, stream>>>(
        dtb, xc, xdbl, a_log + lo*DI*DSTATE, hendb, sdtb);
    scan_p2<<<dim3(Bsz*DSTATE*DI/256), blk, 0, stream>>>(
        hendb, sdtb, a_log + lo*DI*DSTATE);
    scan_p3<<<dim3(Bsz*NCH*(DI/256)), blk, 0, stream>>>(
        dtb, xc, xdbl, zb, a_log + lo*DI*DSTATE, d_par + lo*DI, hendb, ybf);
    // 6. mo = y @ out_proj^T  (256-tile BN=128, N=1024, K=2048)
    gemm2<0,false,128,false><<<dim3(8, 32), blk5, 0, stream>>>(
        ybf, DI, out_wb + lo*D*DI, DI, nullptr, mo, nullptr, D, DI);
    // 7. hm = gelu(mo @ w1^T + b1)  (256-tile, N=2048, K=1024)
    gemm2<2,true,256,false><<<dim3(8, 32), blk5, 0, stream>>>(
        mo, D, w1b, D, b1, hm, nullptr, 2*D, D);
    // 8. t2 = gelu(hm @ w2^T + b2)  (256-tile BN=128, N=1024, K=2048)
    gemm2<2,true,128,false><<<dim3(8, 32), blk5, 0, stream>>>(
        hm, 2*D, w2b, 2*D, b2, t2, nullptr, D, 2*D);
    // 9. x = rmsnorm(t2 + residual) -> out (f32) + xbf (bf16)
    add_rmsnorm<true,true><<<dim3(ML), blk, 0, stream>>>(t2, xcur, ln_w, out, xbf);
    xcur = out;
  }
  // final: rmsnorm(x + residual2)
  add_rmsnorm<false,false><<<dim3(ML), blk, 0, stream>>>(out, x0, ln2_w, out, nullptr);
}